// Round 1
// baseline (480.000 us; speedup 1.0000x reference)
//
#include <hip/hip_runtime.h>
#include <hip/hip_bf16.h>

typedef __attribute__((ext_vector_type(8))) short  bf16x8;
typedef __attribute__((ext_vector_type(4))) float  f32x4;
typedef __attribute__((ext_vector_type(4))) int    i32x4;
typedef __attribute__((ext_vector_type(4))) unsigned short u16x4;
typedef __attribute__((ext_vector_type(8))) unsigned short u16x8;

__device__ __forceinline__ unsigned short f2bf(float f) {
    unsigned int u = __builtin_bit_cast(unsigned int, f);
    u += 0x7FFFu + ((u >> 16) & 1u);   // RNE
    return (unsigned short)(u >> 16);
}
__device__ __forceinline__ float bf2f(unsigned short h) {
    unsigned int u = ((unsigned int)h) << 16;
    return __builtin_bit_cast(float, u);
}

// ---------------- convert x (fp32 -> bf16), 8 elems/thread ----------------
__global__ void cvt_x_kernel(const float* __restrict__ in, unsigned short* __restrict__ out, int n8) {
    int idx = blockIdx.x * blockDim.x + threadIdx.x;
    int stride = gridDim.x * blockDim.x;
    for (int i = idx; i < n8; i += stride) {
        f32x4 a = reinterpret_cast<const f32x4*>(in)[i*2];
        f32x4 b = reinterpret_cast<const f32x4*>(in)[i*2+1];
        u16x8 o;
        o[0]=f2bf(a[0]); o[1]=f2bf(a[1]); o[2]=f2bf(a[2]); o[3]=f2bf(a[3]);
        o[4]=f2bf(b[0]); o[5]=f2bf(b[1]); o[6]=f2bf(b[2]); o[7]=f2bf(b[3]);
        reinterpret_cast<u16x8*>(out)[i] = o;
    }
}

// ---------------- transpose+convert weight: W(K=1024,N=1024) fp32 -> WT(N,K) bf16 ----------------
__global__ void tr_w_kernel(const float* __restrict__ W, unsigned short* __restrict__ WT) {
    __shared__ float tile[32][33];
    int tx = threadIdx.x, ty = threadIdx.y;         // (32,8)
    int n0 = blockIdx.x * 32, k0 = blockIdx.y * 32;
#pragma unroll
    for (int j = 0; j < 4; ++j)
        tile[ty + j*8][tx] = W[(size_t)(k0 + ty + j*8) * 1024 + n0 + tx];
    __syncthreads();
#pragma unroll
    for (int j = 0; j < 4; ++j)
        WT[(size_t)(n0 + ty + j*8) * 1024 + k0 + tx] = f2bf(tile[tx][ty + j*8]);
}

// ---------------- bf16 GEMM: C = A(MxK) * BT(NxK)^T + bias ----------------
// MODE 0: bf16 out, (B,H,S,64) head layout   (Q, K)
// MODE 1: fp32 out, plain (M,N)              (final O projection)
// MODE 2: bf16 out, transposed (B,H,64,S)    (V -> Vt)
#define BM 128
#define BN 128
#define BKK 64

template<int MODE>
__global__ __launch_bounds__(256) void gemm_bf16(
    const unsigned short* __restrict__ A,
    const unsigned short* __restrict__ BT,
    const float* __restrict__ bias,
    void* __restrict__ Cout,
    int M, int N, int K)
{
    __shared__ __align__(16) unsigned short As[BM * BKK];
    __shared__ __align__(16) unsigned short Bs[BN * BKK];

    const int tid  = threadIdx.x;
    const int lane = tid & 63;
    const int w    = tid >> 6;
    const int wm   = w >> 1, wn = w & 1;
    const int m0   = blockIdx.y * BM;
    const int n0   = blockIdx.x * BN;

    f32x4 acc[4][4] = {};

    for (int k0 = 0; k0 < K; k0 += BKK) {
        // stage A,B tiles: 1024 16B-chunks each, 4 per thread, XOR-swizzled 16B slots within 128B rows
#pragma unroll
        for (int j = 0; j < 4; ++j) {
            int c = j * 256 + tid;
            int r = c >> 3, s = c & 7;
            i32x4 va = *reinterpret_cast<const i32x4*>(&A [(size_t)(m0 + r) * K + k0 + s * 8]);
            *reinterpret_cast<i32x4*>(&As[r * 64 + ((s ^ (r & 7)) << 3)]) = va;
            i32x4 vb = *reinterpret_cast<const i32x4*>(&BT[(size_t)(n0 + r) * K + k0 + s * 8]);
            *reinterpret_cast<i32x4*>(&Bs[r * 64 + ((s ^ (r & 7)) << 3)]) = vb;
        }
        __syncthreads();
#pragma unroll
        for (int kc = 0; kc < 2; ++kc) {
            bf16x8 af[4], bfr[4];
            int slog = kc * 4 + (lane >> 4);
#pragma unroll
            for (int t = 0; t < 4; ++t) {
                int row = wm * 64 + t * 16 + (lane & 15);
                af[t]  = *reinterpret_cast<const bf16x8*>(&As[row * 64 + ((slog ^ (row & 7)) << 3)]);
                int col = wn * 64 + t * 16 + (lane & 15);
                bfr[t] = *reinterpret_cast<const bf16x8*>(&Bs[col * 64 + ((slog ^ (col & 7)) << 3)]);
            }
#pragma unroll
            for (int mt = 0; mt < 4; ++mt)
#pragma unroll
                for (int nt = 0; nt < 4; ++nt)
                    acc[mt][nt] = __builtin_amdgcn_mfma_f32_16x16x32_bf16(af[mt], bfr[nt], acc[mt][nt], 0, 0, 0);
        }
        __syncthreads();
    }

    // epilogue. C/D layout: col = lane&15, row = (lane>>4)*4 + r  [verified mapping]
#pragma unroll
    for (int mt = 0; mt < 4; ++mt) {
#pragma unroll
        for (int nt = 0; nt < 4; ++nt) {
            int n     = n0 + wn * 64 + nt * 16 + (lane & 15);
            int mbase = m0 + wm * 64 + mt * 16 + ((lane >> 4) << 2);
            float bv  = bias[n];
            if (MODE == 0) {
                int h = n >> 6, hd = n & 63;
#pragma unroll
                for (int r = 0; r < 4; ++r) {
                    int m = mbase + r;
                    int b = m >> 11, s = m & 2047;
                    ((unsigned short*)Cout)[((size_t)((b << 4) | h) * 2048 + s) * 64 + hd] = f2bf(acc[mt][nt][r] + bv);
                }
            } else if (MODE == 1) {
#pragma unroll
                for (int r = 0; r < 4; ++r)
                    ((float*)Cout)[(size_t)(mbase + r) * N + n] = acc[mt][nt][r] + bv;
            } else {
                int h = n >> 6, hd = n & 63;
                int b = mbase >> 11, s = mbase & 2047;
                u16x4 pk;
#pragma unroll
                for (int r = 0; r < 4; ++r) pk[r] = f2bf(acc[mt][nt][r] + bv);
                *reinterpret_cast<u16x4*>(&((unsigned short*)Cout)[((size_t)((b << 4) | h) * 64 + hd) * 2048 + s]) = pk;
            }
        }
    }
}

// ---------------- c[b,h,d] = sum_k ds[b,k] * V[b,h,k,d]  (reads Vt) ----------------
__global__ void dock_c_kernel(const float* __restrict__ ds, const unsigned short* __restrict__ Vt,
                              float* __restrict__ cvec) {
    __shared__ float red[256];
    int bh = blockIdx.x;          // 32 blocks
    int b  = bh >> 4;
    int t  = threadIdx.x;
    int d  = t & 63, sl = t >> 6; // 4 k-slices of 512
    const unsigned short* vrow = &Vt[(size_t)bh * 131072 + (size_t)d * 2048 + sl * 512];
    const float* dsr = &ds[b * 2048 + sl * 512];
    float sum = 0.f;
    for (int k = 0; k < 512; k += 8) {
        bf16x8 v = *reinterpret_cast<const bf16x8*>(&vrow[k]);
#pragma unroll
        for (int i = 0; i < 8; ++i) sum += dsr[k + i] * bf2f((unsigned short)v[i]);
    }
    red[t] = sum;
    __syncthreads();
    if (t < 64) cvec[bh * 64 + t] = red[t] + red[64 + t] + red[128 + t] + red[192 + t];
}

// ---------------- flash attention, 4 waves x 16 q-rows, KVBLK=64 ----------------
__global__ __launch_bounds__(256) void attn_kernel(
    const unsigned short* __restrict__ Q,   // (BH, S, 64)
    const unsigned short* __restrict__ Kb,  // (BH, S, 64)
    const unsigned short* __restrict__ Vt,  // (BH, 64, S)
    const float* __restrict__ cvec,         // (BH, 64)
    const float* __restrict__ alpha_p,
    unsigned short* __restrict__ ctx)       // (B, S, 1024)
{
    __shared__ __align__(16) float Pl[4][1024];   // per-wave 16x64 fp32, swizzled
    const int tid = threadIdx.x, lane = tid & 63, w = tid >> 6;
    const int bh = blockIdx.x >> 5;
    const int qt = blockIdx.x & 31;
    const int q0 = qt * 64 + w * 16;
    const size_t hb = (size_t)bh * 2048 * 64;
    const float alpha = *alpha_p;

    // Q fragments (A operand): row = lane&15, k = kc*32 + (lane>>4)*8 + i
    bf16x8 qf[2];
    {
        int qrow = q0 + (lane & 15);
#pragma unroll
        for (int kc = 0; kc < 2; ++kc)
            qf[kc] = *reinterpret_cast<const bf16x8*>(&Q[hb + (size_t)qrow * 64 + kc * 32 + ((lane >> 4) << 3)]);
    }

    f32x4 oacc[4] = {};
    float mrow[4] = {-1e30f, -1e30f, -1e30f, -1e30f};
    float lrow[4] = {0.f, 0.f, 0.f, 0.f};
    float* Pw = &Pl[w][0];

    for (int kv0 = 0; kv0 < 2048; kv0 += 64) {
        // ---- scores: S = Q K^T, 16x64 per wave ----
        f32x4 sacc[4] = {};
#pragma unroll
        for (int kc = 0; kc < 2; ++kc) {
            bf16x8 kf[4];
#pragma unroll
            for (int nt = 0; nt < 4; ++nt) {
                int krow = kv0 + nt * 16 + (lane & 15);
                kf[nt] = *reinterpret_cast<const bf16x8*>(&Kb[hb + (size_t)krow * 64 + kc * 32 + ((lane >> 4) << 3)]);
            }
#pragma unroll
            for (int nt = 0; nt < 4; ++nt)
                sacc[nt] = __builtin_amdgcn_mfma_f32_16x16x32_bf16(qf[kc], kf[nt], sacc[nt], 0, 0, 0);
        }
#pragma unroll
        for (int nt = 0; nt < 4; ++nt) sacc[nt] *= 0.125f;   // 1/sqrt(64)

        // ---- online softmax (rows live in 16-lane groups) ----
#pragma unroll
        for (int r = 0; r < 4; ++r) {
            float tm = fmaxf(fmaxf(sacc[0][r], sacc[1][r]), fmaxf(sacc[2][r], sacc[3][r]));
#pragma unroll
            for (int off = 8; off >= 1; off >>= 1) tm = fmaxf(tm, __shfl_xor(tm, off, 64));
            float mn = fmaxf(mrow[r], tm);
            float sc = __expf(mrow[r] - mn);
            float ts = 0.f;
#pragma unroll
            for (int nt = 0; nt < 4; ++nt) {
                float p = __expf(sacc[nt][r] - mn);
                sacc[nt][r] = p;
                ts += p;
            }
#pragma unroll
            for (int off = 8; off >= 1; off >>= 1) ts += __shfl_xor(ts, off, 64);
            lrow[r] = lrow[r] * sc + ts;
            mrow[r] = mn;
#pragma unroll
            for (int nt = 0; nt < 4; ++nt) oacc[nt][r] *= sc;
        }

        // ---- P through per-wave LDS (C-layout -> A-layout), fp32, 16B-slot XOR swizzle ----
#pragma unroll
        for (int nt = 0; nt < 4; ++nt)
#pragma unroll
            for (int r = 0; r < 4; ++r) {
                int pr = ((lane >> 4) << 2) + r, pc = nt * 16 + (lane & 15);
                int slot = pc >> 2;
                Pw[pr * 64 + ((slot ^ (pr & 7)) << 2) + (pc & 3)] = sacc[nt][r];
            }
        // same-wave RAW on LDS: compiler inserts lgkmcnt waits

#pragma unroll
        for (int kc = 0; kc < 2; ++kc) {
            int prow = lane & 15;
            int c0 = kc * 32 + ((lane >> 4) << 3);
            float pv[8];
#pragma unroll
            for (int half = 0; half < 2; ++half) {
                int slot = (c0 >> 2) + half;
                f32x4 t = *reinterpret_cast<const f32x4*>(&Pw[prow * 64 + ((slot ^ (prow & 7)) << 2)]);
                pv[half*4+0] = t[0]; pv[half*4+1] = t[1]; pv[half*4+2] = t[2]; pv[half*4+3] = t[3];
            }
            bf16x8 pf;
#pragma unroll
            for (int i = 0; i < 8; ++i) pf[i] = (short)f2bf(pv[i]);

            bf16x8 vf[4];
#pragma unroll
            for (int nt = 0; nt < 4; ++nt) {
                int hd = nt * 16 + (lane & 15);
                vf[nt] = *reinterpret_cast<const bf16x8*>(&Vt[hb + (size_t)hd * 2048 + kv0 + kc * 32 + ((lane >> 4) << 3)]);
            }
#pragma unroll
            for (int nt = 0; nt < 4; ++nt)
                oacc[nt] = __builtin_amdgcn_mfma_f32_16x16x32_bf16(pf, vf[nt], oacc[nt], 0, 0, 0);
        }
    }

    // ---- epilogue: ctx = (1-a)*O/l + a*c  -> bf16 (B,S,1024) ----
    int b = bh >> 4, h = bh & 15;
#pragma unroll
    for (int nt = 0; nt < 4; ++nt) {
        int hd = nt * 16 + (lane & 15);
        float cv = cvec[bh * 64 + hd];
#pragma unroll
        for (int r = 0; r < 4; ++r) {
            int s = q0 + ((lane >> 4) << 2) + r;
            float v = (1.f - alpha) * (oacc[nt][r] / lrow[r]) + alpha * cv;
            ctx[((size_t)(b * 2048 + s)) * 1024 + h * 64 + hd] = f2bf(v);
        }
    }
}

// ---------------- launch ----------------
extern "C" void kernel_launch(void* const* d_in, const int* in_sizes, int n_in,
                              void* d_out, int out_size, void* d_ws, size_t ws_size,
                              hipStream_t stream) {
    const float* x     = (const float*)d_in[0];
    const float* ds    = (const float*)d_in[1];
    const float* q_w   = (const float*)d_in[2];
    const float* q_b   = (const float*)d_in[3];
    const float* k_w   = (const float*)d_in[4];
    const float* k_b   = (const float*)d_in[5];
    const float* v_w   = (const float*)d_in[6];
    const float* v_b   = (const float*)d_in[7];
    const float* o_w   = (const float*)d_in[8];
    const float* o_b   = (const float*)d_in[9];
    const float* alpha = (const float*)d_in[10];

    char* ws = (char*)d_ws;
    const size_t MB = 1024 * 1024;
    unsigned short* xb   = (unsigned short*)(ws);            // 8MB, also reused as ctx
    unsigned short* wqT  = (unsigned short*)(ws + 8  * MB);  // 2MB each
    unsigned short* wkT  = (unsigned short*)(ws + 10 * MB);
    unsigned short* wvT  = (unsigned short*)(ws + 12 * MB);
    unsigned short* woT  = (unsigned short*)(ws + 14 * MB);
    unsigned short* Qb   = (unsigned short*)(ws + 16 * MB);  // 8MB
    unsigned short* Kb   = (unsigned short*)(ws + 24 * MB);  // 8MB
    unsigned short* Vt   = (unsigned short*)(ws + 32 * MB);  // 8MB
    float*          cvec = (float*)         (ws + 40 * MB);  // 8KB
    unsigned short* ctxb = xb;                               // alias: xb dead after V GEMM

    const int M = 4096, N = 1024, K = 1024;

    cvt_x_kernel<<<2048, 256, 0, stream>>>(x, xb, M * K / 8);

    dim3 tb(32, 8);
    dim3 tg(32, 32);
    tr_w_kernel<<<tg, tb, 0, stream>>>(q_w, wqT);
    tr_w_kernel<<<tg, tb, 0, stream>>>(k_w, wkT);
    tr_w_kernel<<<tg, tb, 0, stream>>>(v_w, wvT);
    tr_w_kernel<<<tg, tb, 0, stream>>>(o_w, woT);

    dim3 gg(N / BN, M / BM);
    gemm_bf16<0><<<gg, 256, 0, stream>>>(xb, wqT, q_b, Qb, M, N, K);
    gemm_bf16<0><<<gg, 256, 0, stream>>>(xb, wkT, k_b, Kb, M, N, K);
    gemm_bf16<2><<<gg, 256, 0, stream>>>(xb, wvT, v_b, Vt, M, N, K);

    dock_c_kernel<<<32, 256, 0, stream>>>(ds, Vt, cvec);

    attn_kernel<<<1024, 256, 0, stream>>>(Qb, Kb, Vt, cvec, alpha, ctxb);

    gemm_bf16<1><<<gg, 256, 0, stream>>>(ctxb, woT, o_b, d_out, M, N, K);
}

// Round 2
// 215.300 us; speedup vs baseline: 2.2294x; 2.2294x over previous
//
#include <hip/hip_runtime.h>
#include <hip/hip_bf16.h>

typedef __attribute__((ext_vector_type(8)))  short bf16x8;
typedef __attribute__((ext_vector_type(4)))  float f32x4;
typedef __attribute__((ext_vector_type(16))) float f32x16;
typedef __attribute__((ext_vector_type(4)))  int   i32x4;
typedef __attribute__((ext_vector_type(4)))  unsigned short u16x4;
typedef __attribute__((ext_vector_type(8)))  unsigned short u16x8;

__device__ __forceinline__ unsigned short f2bf(float f) {
    unsigned int u = __builtin_bit_cast(unsigned int, f);
    u += 0x7FFFu + ((u >> 16) & 1u);   // RNE
    return (unsigned short)(u >> 16);
}
__device__ __forceinline__ float bf2f(unsigned short h) {
    unsigned int u = ((unsigned int)h) << 16;
    return __builtin_bit_cast(float, u);
}
__device__ __forceinline__ bf16x8 ld16(const unsigned short* p) {
    return *reinterpret_cast<const bf16x8*>(p);
}

// ---------------- convert x (fp32 -> bf16), 8 elems/thread ----------------
__global__ void cvt_x_kernel(const float* __restrict__ in, unsigned short* __restrict__ out, int n8) {
    int idx = blockIdx.x * blockDim.x + threadIdx.x;
    int stride = gridDim.x * blockDim.x;
    for (int i = idx; i < n8; i += stride) {
        f32x4 a = reinterpret_cast<const f32x4*>(in)[i*2];
        f32x4 b = reinterpret_cast<const f32x4*>(in)[i*2+1];
        u16x8 o;
        o[0]=f2bf(a[0]); o[1]=f2bf(a[1]); o[2]=f2bf(a[2]); o[3]=f2bf(a[3]);
        o[4]=f2bf(b[0]); o[5]=f2bf(b[1]); o[6]=f2bf(b[2]); o[7]=f2bf(b[3]);
        reinterpret_cast<u16x8*>(out)[i] = o;
    }
}

// ---------------- transpose+convert all 4 weights: W(K,N) fp32 -> WT(N,K) bf16 ----------------
__global__ void tr_w_kernel(const float* __restrict__ q_w, const float* __restrict__ k_w,
                            const float* __restrict__ v_w, const float* __restrict__ o_w,
                            unsigned short* __restrict__ WT) {
    __shared__ float tile[32][33];
    const float* W = (blockIdx.z == 0) ? q_w : (blockIdx.z == 1) ? k_w : (blockIdx.z == 2) ? v_w : o_w;
    unsigned short* dst = WT + (size_t)blockIdx.z * 1024 * 1024;
    int tx = threadIdx.x, ty = threadIdx.y;         // (32,8)
    int n0 = blockIdx.x * 32, k0 = blockIdx.y * 32;
#pragma unroll
    for (int j = 0; j < 4; ++j)
        tile[ty + j*8][tx] = W[(size_t)(k0 + ty + j*8) * 1024 + n0 + tx];
    __syncthreads();
#pragma unroll
    for (int j = 0; j < 4; ++j)
        dst[(size_t)(n0 + ty + j*8) * 1024 + k0 + tx] = f2bf(tile[tx][ty + j*8]);
}

// ---------------- merged QKV GEMM: [Q|K|V] = x * [wq|wk|wv]^T, m97-style gload_lds staging ----------------
__global__ __launch_bounds__(256) void gemm_qkv(
    const unsigned short* __restrict__ A,     // (4096,1024) bf16
    const unsigned short* __restrict__ WT,    // (3072,1024) bf16
    const float* __restrict__ qb, const float* __restrict__ kbias, const float* __restrict__ vbias,
    unsigned short* __restrict__ Qo, unsigned short* __restrict__ Ko, unsigned short* __restrict__ Vto)
{
    __shared__ __align__(16) unsigned short As[128*64];
    __shared__ __align__(16) unsigned short Bs[128*64];
    const int tid = threadIdx.x, lane = tid & 63, w = tid >> 6;
    const int wm = w >> 1, wn = w & 1;
    const int m0 = blockIdx.y * 128, n0 = blockIdx.x * 128;   // grid (24,32)
    const int K = 1024;
    f32x4 acc[4][4] = {};
    for (int k0 = 0; k0 < K; k0 += 64) {
#pragma unroll
        for (int j = 0; j < 4; ++j) {
            const int c = j*256 + tid, r = c >> 3, s = c & 7;
            __builtin_amdgcn_global_load_lds(
                (const __attribute__((address_space(1))) void*)&A[(size_t)(m0+r)*K + k0 + s*8],
                (__attribute__((address_space(3))) void*)&As[(size_t)c*8], 16, 0, 0);
            __builtin_amdgcn_global_load_lds(
                (const __attribute__((address_space(1))) void*)&WT[(size_t)(n0+r)*K + k0 + s*8],
                (__attribute__((address_space(3))) void*)&Bs[(size_t)c*8], 16, 0, 0);
        }
        __syncthreads();
#pragma unroll
        for (int kc = 0; kc < 2; ++kc) {
            bf16x8 af[4], bfr[4];
            const int slog = kc*4 + (lane >> 4);
#pragma unroll
            for (int t = 0; t < 4; ++t) {
                const int row = wm*64 + t*16 + (lane & 15);
                af[t]  = ld16(&As[row*64 + slog*8]);
                const int col = wn*64 + t*16 + (lane & 15);
                bfr[t] = ld16(&Bs[col*64 + slog*8]);
            }
#pragma unroll
            for (int mt = 0; mt < 4; ++mt)
#pragma unroll
                for (int nt = 0; nt < 4; ++nt)
                    acc[mt][nt] = __builtin_amdgcn_mfma_f32_16x16x32_bf16(af[mt], bfr[nt], acc[mt][nt], 0, 0, 0);
        }
        __syncthreads();
    }
    const int mat = n0 >> 10;
    if (mat == 2) {
        // V -> Vt (B,H,64,S)
#pragma unroll
        for (int mt = 0; mt < 4; ++mt)
#pragma unroll
        for (int nt = 0; nt < 4; ++nt) {
            const int nl = (n0 & 1023) + wn*64 + nt*16 + (lane & 15);
            const int h = nl >> 6, hd = nl & 63;
            const int mbase = m0 + wm*64 + mt*16 + ((lane >> 4) << 2);
            const int b = mbase >> 11, s = mbase & 2047;
            const float bv = vbias[nl];
            u16x4 pk;
#pragma unroll
            for (int r = 0; r < 4; ++r) pk[r] = f2bf(acc[mt][nt][r] + bv);
            *reinterpret_cast<u16x4*>(&Vto[((size_t)((b << 4) | h) * 64 + hd) * 2048 + s]) = pk;
        }
    } else {
        unsigned short* outp = mat ? Ko : Qo;
        const float* bias = mat ? kbias : qb;
        const float scale = mat ? 1.0f : 0.125f;    // fold 1/sqrt(64) into Q
#pragma unroll
        for (int mt = 0; mt < 4; ++mt)
#pragma unroll
        for (int nt = 0; nt < 4; ++nt) {
            const int nl = (n0 & 1023) + wn*64 + nt*16 + (lane & 15);
            const int h = nl >> 6, hd = nl & 63;
            const int mbase = m0 + wm*64 + mt*16 + ((lane >> 4) << 2);
            const float bv = bias[nl];
#pragma unroll
            for (int r = 0; r < 4; ++r) {
                const int mm2 = mbase + r, b = mm2 >> 11, s = mm2 & 2047;
                outp[((size_t)((b << 4) | h) * 2048 + s) * 64 + hd] = f2bf((acc[mt][nt][r] + bv) * scale);
            }
        }
    }
}

// ---------------- O projection GEMM: fp32 out ----------------
__global__ __launch_bounds__(256) void gemm_o(
    const unsigned short* __restrict__ A, const unsigned short* __restrict__ WT,
    const float* __restrict__ bias, float* __restrict__ Cout)
{
    __shared__ __align__(16) unsigned short As[128*64];
    __shared__ __align__(16) unsigned short Bs[128*64];
    const int tid = threadIdx.x, lane = tid & 63, w = tid >> 6;
    const int wm = w >> 1, wn = w & 1;
    const int m0 = blockIdx.y * 128, n0 = blockIdx.x * 128;   // grid (8,32)
    const int K = 1024;
    f32x4 acc[4][4] = {};
    for (int k0 = 0; k0 < K; k0 += 64) {
#pragma unroll
        for (int j = 0; j < 4; ++j) {
            const int c = j*256 + tid, r = c >> 3, s = c & 7;
            __builtin_amdgcn_global_load_lds(
                (const __attribute__((address_space(1))) void*)&A[(size_t)(m0+r)*K + k0 + s*8],
                (__attribute__((address_space(3))) void*)&As[(size_t)c*8], 16, 0, 0);
            __builtin_amdgcn_global_load_lds(
                (const __attribute__((address_space(1))) void*)&WT[(size_t)(n0+r)*K + k0 + s*8],
                (__attribute__((address_space(3))) void*)&Bs[(size_t)c*8], 16, 0, 0);
        }
        __syncthreads();
#pragma unroll
        for (int kc = 0; kc < 2; ++kc) {
            bf16x8 af[4], bfr[4];
            const int slog = kc*4 + (lane >> 4);
#pragma unroll
            for (int t = 0; t < 4; ++t) {
                const int row = wm*64 + t*16 + (lane & 15);
                af[t]  = ld16(&As[row*64 + slog*8]);
                const int col = wn*64 + t*16 + (lane & 15);
                bfr[t] = ld16(&Bs[col*64 + slog*8]);
            }
#pragma unroll
            for (int mt = 0; mt < 4; ++mt)
#pragma unroll
                for (int nt = 0; nt < 4; ++nt)
                    acc[mt][nt] = __builtin_amdgcn_mfma_f32_16x16x32_bf16(af[mt], bfr[nt], acc[mt][nt], 0, 0, 0);
        }
        __syncthreads();
    }
#pragma unroll
    for (int mt = 0; mt < 4; ++mt)
#pragma unroll
    for (int nt = 0; nt < 4; ++nt) {
        const int n = n0 + wn*64 + nt*16 + (lane & 15);
        const int mbase = m0 + wm*64 + mt*16 + ((lane >> 4) << 2);
        const float bv = bias[n];
#pragma unroll
        for (int r = 0; r < 4; ++r)
            Cout[(size_t)(mbase + r) * 1024 + n] = acc[mt][nt][r] + bv;
    }
}

// ---------------- c[b,h,d] = sum_k ds[b,k] * V[b,h,k,d]  (reads Vt), 256 blocks + atomics ----------------
__global__ void dock_c_kernel(const float* __restrict__ ds, const unsigned short* __restrict__ Vt,
                              float* __restrict__ cvec) {
    __shared__ float red[256];
    const int bh = blockIdx.x >> 3, sl = blockIdx.x & 7;
    const int b = bh >> 4;
    const int t = threadIdx.x, d = t & 63, q4 = t >> 6;
    const unsigned short* vrow = &Vt[(size_t)bh * 131072 + (size_t)d * 2048 + sl * 256 + q4 * 64];
    const float* dsr = &ds[b * 2048 + sl * 256 + q4 * 64];
    float sum = 0.f;
#pragma unroll
    for (int k = 0; k < 64; k += 8) {
        bf16x8 v = ld16(&vrow[k]);
#pragma unroll
        for (int i = 0; i < 8; ++i) sum += dsr[k + i] * bf2f((unsigned short)v[i]);
    }
    red[t] = sum;
    __syncthreads();
    if (t < 64) atomicAdd(&cvec[bh * 64 + t], red[t] + red[64 + t] + red[128 + t] + red[192 + t]);
}

// ---------------- flash attention: swapped QK^T, 32x32 MFMA, in-register softmax ----------------
__global__ __launch_bounds__(256, 2) void attn_kernel(
    const unsigned short* __restrict__ Qp,   // (BH,S,64), pre-scaled by 0.125
    const unsigned short* __restrict__ Kp,   // (BH,S,64)
    const unsigned short* __restrict__ Vp,   // (BH,64,S)
    const float* __restrict__ cvec,          // (BH,64)
    const float* __restrict__ alpha_p,
    unsigned short* __restrict__ ctx)        // (B,S,1024)
{
    __shared__ float sml[4][32];
    const int tid = threadIdx.x, lane = tid & 63, w = tid >> 6;
    const int hi = lane >> 5, ln = lane & 31;
    const int bh = blockIdx.x >> 4, qt = blockIdx.x & 15;   // grid 512 = 32 bh x 16 qtiles
    const int q0 = qt * 128 + w * 32;                        // 32 q-rows per wave
    const size_t hb = (size_t)bh * (2048 * 64);
    const float alpha = *alpha_p;

    // Q as B-operand: col=ln (q-row), k = ks*16 + hi*8 + i
    bf16x8 qf[4];
    {
        const unsigned short* qr = &Qp[hb + (size_t)(q0 + ln) * 64 + hi * 8];
#pragma unroll
        for (int ks = 0; ks < 4; ++ks) qf[ks] = ld16(qr + ks * 16);
    }

    f32x16 oacc0 = {}, oacc1 = {};
    float m = -1e30f, l = 0.f;

    const unsigned short* kbase  = &Kp[hb + (size_t)ln * 64 + hi * 8];
    const unsigned short* vbase0 = &Vp[hb + (size_t)ln * 2048 + hi * 8];
    const unsigned short* vbase1 = vbase0 + (size_t)32 * 2048;

    bf16x8 kfa[8], kfb[8];
#pragma unroll
    for (int t2 = 0; t2 < 2; ++t2)
#pragma unroll
    for (int ks = 0; ks < 4; ++ks)
        kfa[t2*4+ks] = ld16(kbase + (t2*32)*64 + ks*16);

    auto body = [&](bf16x8 (&kc)[8], bf16x8 (&kn)[8], int it) {
        // prefetch next K tile into the other buffer
        if (it + 1 < 32) {
            const unsigned short* knp = kbase + (size_t)(it + 1) * 4096;
#pragma unroll
            for (int t2 = 0; t2 < 2; ++t2)
#pragma unroll
            for (int ks = 0; ks < 4; ++ks)
                kn[t2*4+ks] = ld16(knp + (t2*32)*64 + ks*16);
        }
        // V for this iter (issued early; consumed after softmax)
        bf16x8 vf[8];
#pragma unroll
        for (int ks = 0; ks < 4; ++ks) {
            vf[ks]   = ld16(vbase0 + it*64 + ks*16);
            vf[4+ks] = ld16(vbase1 + it*64 + ks*16);
        }
        // S^T = K Q^T : lane holds 32 scores of q-row (q0+ln); kv = 32*tile + (r&3)+8*(r>>2)+4*hi
        f32x16 st0 = {}, st1 = {};
#pragma unroll
        for (int ks = 0; ks < 4; ++ks) {
            st0 = __builtin_amdgcn_mfma_f32_32x32x16_bf16(kc[ks],   qf[ks], st0, 0, 0, 0);
            st1 = __builtin_amdgcn_mfma_f32_32x32x16_bf16(kc[4+ks], qf[ks], st1, 0, 0, 0);
        }
        // row max (lane-local tree + one xor-32)
        float mx[8];
#pragma unroll
        for (int r = 0; r < 8; ++r)
            mx[r] = fmaxf(fmaxf(st0[r], st0[r+8]), fmaxf(st1[r], st1[r+8]));
        float tm = fmaxf(fmaxf(fmaxf(mx[0],mx[1]), fmaxf(mx[2],mx[3])),
                         fmaxf(fmaxf(mx[4],mx[5]), fmaxf(mx[6],mx[7])));
        tm = fmaxf(tm, __shfl_xor(tm, 32, 64));
        // defer-max rescale (T13): rare after iter 0
        if (__any(tm > m + 8.f)) {
            float mn = fmaxf(m, tm);
            float sc = __expf(m - mn);
            m = mn;
            l *= sc;
            if (hi == 0) sml[w][ln] = sc;          // broadcast per-q-row scale
#pragma unroll
            for (int m4 = 0; m4 < 4; ++m4) {
                f32x4 sv = *reinterpret_cast<const f32x4*>(&sml[w][m4*8 + hi*4]);
#pragma unroll
                for (int r3 = 0; r3 < 4; ++r3) {
                    oacc0[m4*4+r3] *= sv[r3];
                    oacc1[m4*4+r3] *= sv[r3];
                }
            }
        }
        float p0a[16], p1a[16];
#pragma unroll
        for (int r = 0; r < 16; ++r) {
            p0a[r] = __expf(st0[r] - m);
            p1a[r] = __expf(st1[r] - m);
        }
        float s8[8];
#pragma unroll
        for (int r = 0; r < 8; ++r)
            s8[r] = (p0a[r] + p0a[r+8]) + (p1a[r] + p1a[r+8]);
        l += ((s8[0]+s8[1])+(s8[2]+s8[3])) + ((s8[4]+s8[5])+(s8[6]+s8[7]));

        // pack P -> bf16 pairs: Wp[m4][jj] = (kv 32t+8m4+4hi+2jj , +1)
        unsigned int Wp0[4][2], Wp1[4][2];
#pragma unroll
        for (int m4 = 0; m4 < 4; ++m4)
#pragma unroll
        for (int jj = 0; jj < 2; ++jj) {
            asm("v_cvt_pk_bf16_f32 %0, %1, %2" : "=v"(Wp0[m4][jj]) : "v"(p0a[m4*4+jj*2]), "v"(p0a[m4*4+jj*2+1]));
            asm("v_cvt_pk_bf16_f32 %0, %1, %2" : "=v"(Wp1[m4][jj]) : "v"(p1a[m4*4+jj*2]), "v"(p1a[m4*4+jj*2+1]));
        }
        // exchange the cross-half words (lane c <-> c+32)
        unsigned int Xp0[2][2], Xp1[2][2];
#pragma unroll
        for (int tp = 0; tp < 2; ++tp)
#pragma unroll
        for (int jj = 0; jj < 2; ++jj) {
            int s0 = hi ? (int)Wp0[2*tp][jj] : (int)Wp0[2*tp+1][jj];
            int s1 = hi ? (int)Wp1[2*tp][jj] : (int)Wp1[2*tp+1][jj];
            Xp0[tp][jj] = (unsigned int)__shfl_xor(s0, 32, 64);
            Xp1[tp][jj] = (unsigned int)__shfl_xor(s1, 32, 64);
        }
        // PV: A-frag(ks) = P[q=ln][kv = 16ks + 8hi + i]
#pragma unroll
        for (int ks = 0; ks < 4; ++ks) {
            const int tp = ks & 1;
            unsigned int A0, A1, B0, B1;
            if (ks < 2) {
                A0 = hi ? Wp0[2*tp+1][0] : Wp0[2*tp][0];
                A1 = hi ? Wp0[2*tp+1][1] : Wp0[2*tp][1];
                B0 = Xp0[tp][0]; B1 = Xp0[tp][1];
            } else {
                A0 = hi ? Wp1[2*tp+1][0] : Wp1[2*tp][0];
                A1 = hi ? Wp1[2*tp+1][1] : Wp1[2*tp][1];
                B0 = Xp1[tp][0]; B1 = Xp1[tp][1];
            }
            i32x4 pw;
            pw[0] = (int)(hi ? B0 : A0);
            pw[1] = (int)(hi ? B1 : A1);
            pw[2] = (int)(hi ? A0 : B0);
            pw[3] = (int)(hi ? A1 : B1);
            bf16x8 pf = __builtin_bit_cast(bf16x8, pw);
            oacc0 = __builtin_amdgcn_mfma_f32_32x32x16_bf16(pf, vf[ks],   oacc0, 0, 0, 0);
            oacc1 = __builtin_amdgcn_mfma_f32_32x32x16_bf16(pf, vf[4+ks], oacc1, 0, 0, 0);
        }
    };

    for (int itp = 0; itp < 16; ++itp) {
        body(kfa, kfb, itp*2);
        body(kfb, kfa, itp*2+1);
    }

    // epilogue: ctx = (1-a)*O/l + a*c
    float lf = l + __shfl_xor(l, 32, 64);
    if (hi == 0) sml[w][ln] = 1.0f / lf;
    const int b = bh >> 4, h = bh & 15;
    const float a1 = 1.f - alpha;
    const float cv0 = alpha * cvec[bh*64 + ln];
    const float cv1 = alpha * cvec[bh*64 + 32 + ln];
#pragma unroll
    for (int m4 = 0; m4 < 4; ++m4) {
        f32x4 iv = *reinterpret_cast<const f32x4*>(&sml[w][m4*8 + hi*4]);
#pragma unroll
        for (int r3 = 0; r3 < 4; ++r3) {
            const int row = m4*8 + hi*4 + r3;
            const int s = q0 + row;
            unsigned short* orow = &ctx[((size_t)(b*2048 + s))*1024 + h*64 + ln];
            orow[0]  = f2bf(a1 * oacc0[m4*4+r3] * iv[r3] + cv0);
            orow[32] = f2bf(a1 * oacc1[m4*4+r3] * iv[r3] + cv1);
        }
    }
}

// ---------------- launch ----------------
extern "C" void kernel_launch(void* const* d_in, const int* in_sizes, int n_in,
                              void* d_out, int out_size, void* d_ws, size_t ws_size,
                              hipStream_t stream) {
    const float* x     = (const float*)d_in[0];
    const float* ds    = (const float*)d_in[1];
    const float* q_w   = (const float*)d_in[2];
    const float* q_b   = (const float*)d_in[3];
    const float* k_w   = (const float*)d_in[4];
    const float* k_b   = (const float*)d_in[5];
    const float* v_w   = (const float*)d_in[6];
    const float* v_b   = (const float*)d_in[7];
    const float* o_w   = (const float*)d_in[8];
    const float* o_b   = (const float*)d_in[9];
    const float* alpha = (const float*)d_in[10];

    char* ws = (char*)d_ws;
    const size_t MB = 1024 * 1024;
    unsigned short* xb   = (unsigned short*)(ws);            // 8MB, reused as ctx
    unsigned short* wT   = (unsigned short*)(ws + 8  * MB);  // 8MB: wq|wk|wv|wo transposed bf16
    unsigned short* Qb   = (unsigned short*)(ws + 16 * MB);  // 8MB
    unsigned short* Kb   = (unsigned short*)(ws + 24 * MB);  // 8MB
    unsigned short* Vt   = (unsigned short*)(ws + 32 * MB);  // 8MB
    float*          cvec = (float*)         (ws + 40 * MB);  // 8KB
    unsigned short* ctxb = xb;

    const int M = 4096, K = 1024;

    cvt_x_kernel<<<2048, 256, 0, stream>>>(x, xb, M * K / 8);

    dim3 tb(32, 8);
    dim3 tg(32, 32, 4);
    tr_w_kernel<<<tg, tb, 0, stream>>>(q_w, k_w, v_w, o_w, wT);

    dim3 gqkv(24, 32);
    gemm_qkv<<<gqkv, 256, 0, stream>>>(xb, wT, q_b, k_b, v_b, Qb, Kb, Vt);

    hipMemsetAsync(cvec, 0, 32 * 64 * sizeof(float), stream);
    dock_c_kernel<<<256, 256, 0, stream>>>(ds, Vt, cvec);

    attn_kernel<<<512, 256, 0, stream>>>(Qb, Kb, Vt, cvec, alpha, ctxb);

    dim3 go(8, 32);
    gemm_o<<<go, 256, 0, stream>>>(ctxb, wT + (size_t)3 * MB, o_b, (float*)d_out);
}

// Round 3
// 163.603 us; speedup vs baseline: 2.9339x; 1.3160x over previous
//
#include <hip/hip_runtime.h>
#include <hip/hip_bf16.h>

typedef __attribute__((ext_vector_type(8)))  short bf16x8;
typedef __attribute__((ext_vector_type(4)))  float f32x4;
typedef __attribute__((ext_vector_type(16))) float f32x16;
typedef __attribute__((ext_vector_type(4)))  int   i32x4;
typedef __attribute__((ext_vector_type(4)))  unsigned short u16x4;
typedef __attribute__((ext_vector_type(8)))  unsigned short u16x8;

__device__ __forceinline__ unsigned short f2bf(float f) {
    unsigned int u = __builtin_bit_cast(unsigned int, f);
    u += 0x7FFFu + ((u >> 16) & 1u);   // RNE
    return (unsigned short)(u >> 16);
}
__device__ __forceinline__ float bf2f(unsigned short h) {
    unsigned int u = ((unsigned int)h) << 16;
    return __builtin_bit_cast(float, u);
}
__device__ __forceinline__ bf16x8 ld16(const unsigned short* p) {
    return *reinterpret_cast<const bf16x8*>(p);
}
__device__ __forceinline__ float fexp2(float x) {
    float r; asm("v_exp_f32 %0, %1" : "=v"(r) : "v"(x)); return r;
}

// ---------------- convert x (fp32 -> bf16), 8 elems/thread ----------------
__global__ void cvt_x_kernel(const float* __restrict__ in, unsigned short* __restrict__ out, int n8) {
    int idx = blockIdx.x * blockDim.x + threadIdx.x;
    int stride = gridDim.x * blockDim.x;
    for (int i = idx; i < n8; i += stride) {
        f32x4 a = reinterpret_cast<const f32x4*>(in)[i*2];
        f32x4 b = reinterpret_cast<const f32x4*>(in)[i*2+1];
        u16x8 o;
        o[0]=f2bf(a[0]); o[1]=f2bf(a[1]); o[2]=f2bf(a[2]); o[3]=f2bf(a[3]);
        o[4]=f2bf(b[0]); o[5]=f2bf(b[1]); o[6]=f2bf(b[2]); o[7]=f2bf(b[3]);
        reinterpret_cast<u16x8*>(out)[i] = o;
    }
}

// ---------------- transpose+convert all 4 weights: W(K,N) fp32 -> WT(N,K) bf16 ----------------
__global__ void tr_w_kernel(const float* __restrict__ q_w, const float* __restrict__ k_w,
                            const float* __restrict__ v_w, const float* __restrict__ o_w,
                            unsigned short* __restrict__ WT) {
    __shared__ float tile[32][33];
    const float* W = (blockIdx.z == 0) ? q_w : (blockIdx.z == 1) ? k_w : (blockIdx.z == 2) ? v_w : o_w;
    unsigned short* dst = WT + (size_t)blockIdx.z * 1024 * 1024;
    int tx = threadIdx.x, ty = threadIdx.y;         // (32,8)
    int n0 = blockIdx.x * 32, k0 = blockIdx.y * 32;
#pragma unroll
    for (int j = 0; j < 4; ++j)
        tile[ty + j*8][tx] = W[(size_t)(k0 + ty + j*8) * 1024 + n0 + tx];
    __syncthreads();
#pragma unroll
    for (int j = 0; j < 4; ++j)
        dst[(size_t)(n0 + ty + j*8) * 1024 + k0 + tx] = f2bf(tile[tx][ty + j*8]);
}

// ---------------- merged QKV GEMM: [Q|K|V] = x * [wq|wk|wv]^T, m97-style gload_lds staging ----------------
__global__ __launch_bounds__(256) void gemm_qkv(
    const unsigned short* __restrict__ A,     // (4096,1024) bf16
    const unsigned short* __restrict__ WT,    // (3072,1024) bf16
    const float* __restrict__ qb, const float* __restrict__ kbias, const float* __restrict__ vbias,
    unsigned short* __restrict__ Qo, unsigned short* __restrict__ Ko, unsigned short* __restrict__ Vto)
{
    __shared__ __align__(16) unsigned short As[128*64];
    __shared__ __align__(16) unsigned short Bs[128*64];
    const int tid = threadIdx.x, lane = tid & 63, w = tid >> 6;
    const int wm = w >> 1, wn = w & 1;
    const int m0 = blockIdx.y * 128, n0 = blockIdx.x * 128;   // grid (24,32)
    const int K = 1024;
    f32x4 acc[4][4] = {};
    for (int k0 = 0; k0 < K; k0 += 64) {
#pragma unroll
        for (int j = 0; j < 4; ++j) {
            const int c = j*256 + tid, r = c >> 3, s = c & 7;
            __builtin_amdgcn_global_load_lds(
                (const __attribute__((address_space(1))) void*)&A[(size_t)(m0+r)*K + k0 + s*8],
                (__attribute__((address_space(3))) void*)&As[(size_t)c*8], 16, 0, 0);
            __builtin_amdgcn_global_load_lds(
                (const __attribute__((address_space(1))) void*)&WT[(size_t)(n0+r)*K + k0 + s*8],
                (__attribute__((address_space(3))) void*)&Bs[(size_t)c*8], 16, 0, 0);
        }
        __syncthreads();
#pragma unroll
        for (int kc = 0; kc < 2; ++kc) {
            bf16x8 af[4], bfr[4];
            const int slog = kc*4 + (lane >> 4);
#pragma unroll
            for (int t = 0; t < 4; ++t) {
                const int row = wm*64 + t*16 + (lane & 15);
                af[t]  = ld16(&As[row*64 + slog*8]);
                const int col = wn*64 + t*16 + (lane & 15);
                bfr[t] = ld16(&Bs[col*64 + slog*8]);
            }
#pragma unroll
            for (int mt = 0; mt < 4; ++mt)
#pragma unroll
                for (int nt = 0; nt < 4; ++nt)
                    acc[mt][nt] = __builtin_amdgcn_mfma_f32_16x16x32_bf16(af[mt], bfr[nt], acc[mt][nt], 0, 0, 0);
        }
        __syncthreads();
    }
    const int mat = n0 >> 10;
    if (mat == 2) {
        // V -> Vt (B,H,64,S)
#pragma unroll
        for (int mt = 0; mt < 4; ++mt)
#pragma unroll
        for (int nt = 0; nt < 4; ++nt) {
            const int nl = (n0 & 1023) + wn*64 + nt*16 + (lane & 15);
            const int h = nl >> 6, hd = nl & 63;
            const int mbase = m0 + wm*64 + mt*16 + ((lane >> 4) << 2);
            const int b = mbase >> 11, s = mbase & 2047;
            const float bv = vbias[nl];
            u16x4 pk;
#pragma unroll
            for (int r = 0; r < 4; ++r) pk[r] = f2bf(acc[mt][nt][r] + bv);
            *reinterpret_cast<u16x4*>(&Vto[((size_t)((b << 4) | h) * 64 + hd) * 2048 + s]) = pk;
        }
    } else {
        unsigned short* outp = mat ? Ko : Qo;
        const float* bias = mat ? kbias : qb;
        // Q: fold 1/sqrt(64) * log2(e) so attention works in exp2 domain
        const float scale = mat ? 1.0f : 0.180336881f;
#pragma unroll
        for (int mt = 0; mt < 4; ++mt)
#pragma unroll
        for (int nt = 0; nt < 4; ++nt) {
            const int nl = (n0 & 1023) + wn*64 + nt*16 + (lane & 15);
            const int h = nl >> 6, hd = nl & 63;
            const int mbase = m0 + wm*64 + mt*16 + ((lane >> 4) << 2);
            const float bv = bias[nl];
#pragma unroll
            for (int r = 0; r < 4; ++r) {
                const int mm2 = mbase + r, b = mm2 >> 11, s = mm2 & 2047;
                outp[((size_t)((b << 4) | h) * 2048 + s) * 64 + hd] = f2bf((acc[mt][nt][r] + bv) * scale);
            }
        }
    }
}

// ---------------- O projection GEMM: fp32 out ----------------
__global__ __launch_bounds__(256) void gemm_o(
    const unsigned short* __restrict__ A, const unsigned short* __restrict__ WT,
    const float* __restrict__ bias, float* __restrict__ Cout)
{
    __shared__ __align__(16) unsigned short As[128*64];
    __shared__ __align__(16) unsigned short Bs[128*64];
    const int tid = threadIdx.x, lane = tid & 63, w = tid >> 6;
    const int wm = w >> 1, wn = w & 1;
    const int m0 = blockIdx.y * 128, n0 = blockIdx.x * 128;   // grid (8,32)
    const int K = 1024;
    f32x4 acc[4][4] = {};
    for (int k0 = 0; k0 < K; k0 += 64) {
#pragma unroll
        for (int j = 0; j < 4; ++j) {
            const int c = j*256 + tid, r = c >> 3, s = c & 7;
            __builtin_amdgcn_global_load_lds(
                (const __attribute__((address_space(1))) void*)&A[(size_t)(m0+r)*K + k0 + s*8],
                (__attribute__((address_space(3))) void*)&As[(size_t)c*8], 16, 0, 0);
            __builtin_amdgcn_global_load_lds(
                (const __attribute__((address_space(1))) void*)&WT[(size_t)(n0+r)*K + k0 + s*8],
                (__attribute__((address_space(3))) void*)&Bs[(size_t)c*8], 16, 0, 0);
        }
        __syncthreads();
#pragma unroll
        for (int kc = 0; kc < 2; ++kc) {
            bf16x8 af[4], bfr[4];
            const int slog = kc*4 + (lane >> 4);
#pragma unroll
            for (int t = 0; t < 4; ++t) {
                const int row = wm*64 + t*16 + (lane & 15);
                af[t]  = ld16(&As[row*64 + slog*8]);
                const int col = wn*64 + t*16 + (lane & 15);
                bfr[t] = ld16(&Bs[col*64 + slog*8]);
            }
#pragma unroll
            for (int mt = 0; mt < 4; ++mt)
#pragma unroll
                for (int nt = 0; nt < 4; ++nt)
                    acc[mt][nt] = __builtin_amdgcn_mfma_f32_16x16x32_bf16(af[mt], bfr[nt], acc[mt][nt], 0, 0, 0);
        }
        __syncthreads();
    }
#pragma unroll
    for (int mt = 0; mt < 4; ++mt)
#pragma unroll
    for (int nt = 0; nt < 4; ++nt) {
        const int n = n0 + wn*64 + nt*16 + (lane & 15);
        const int mbase = m0 + wm*64 + mt*16 + ((lane >> 4) << 2);
        const float bv = bias[n];
#pragma unroll
        for (int r = 0; r < 4; ++r)
            Cout[(size_t)(mbase + r) * 1024 + n] = acc[mt][nt][r] + bv;
    }
}

// ---------------- c[b,h,d] = sum_k ds[b,k] * V[b,h,k,d]  (reads Vt), 256 blocks + atomics ----------------
__global__ void dock_c_kernel(const float* __restrict__ ds, const unsigned short* __restrict__ Vt,
                              float* __restrict__ cvec) {
    __shared__ float red[256];
    const int bh = blockIdx.x >> 3, sl = blockIdx.x & 7;
    const int b = bh >> 4;
    const int t = threadIdx.x, d = t & 63, q4 = t >> 6;
    const unsigned short* vrow = &Vt[(size_t)bh * 131072 + (size_t)d * 2048 + sl * 256 + q4 * 64];
    const float* dsr = &ds[b * 2048 + sl * 256 + q4 * 64];
    float sum = 0.f;
#pragma unroll
    for (int k = 0; k < 64; k += 8) {
        bf16x8 v = ld16(&vrow[k]);
#pragma unroll
        for (int i = 0; i < 8; ++i) sum += dsr[k + i] * bf2f((unsigned short)v[i]);
    }
    red[t] = sum;
    __syncthreads();
    if (t < 64) atomicAdd(&cvec[bh * 64 + t], red[t] + red[64 + t] + red[128 + t] + red[192 + t]);
}

// ---------------- flash attention: LDS-staged K/V, swapped QK^T, in-register softmax ----------------
__global__ __launch_bounds__(256, 2) void attn_kernel(
    const unsigned short* __restrict__ Qp,   // (BH,S,64), pre-scaled by 0.125*log2e
    const unsigned short* __restrict__ Kp,   // (BH,S,64)
    const unsigned short* __restrict__ Vp,   // (BH,64,S)
    const float* __restrict__ cvec,          // (BH,64)
    const float* __restrict__ alpha_p,
    unsigned short* __restrict__ ctx)        // (B,S,1024)
{
    __shared__ __align__(16) unsigned short Ks[2][4096];   // 2 x 8KB: 64 kv x 64 d, swizzled
    __shared__ __align__(16) unsigned short Vs[2][4096];   // 2 x 8KB: 64 hd x 64 kv, swizzled
    __shared__ float sml[4][32];
    const int tid = threadIdx.x, lane = tid & 63, w = tid >> 6;
    const int hi = lane >> 5, ln = lane & 31;
    const int bh = blockIdx.x >> 4, qt = blockIdx.x & 15;   // grid 512 = 32 bh x 16 qtiles
    const int q0 = qt * 128 + w * 32;                        // 32 q-rows per wave
    const size_t hb = (size_t)bh * (2048 * 64);
    const float alpha = *alpha_p;

    // staging geometry: thread -> (row sr, slot ss); source slot pre-swizzled, LDS dest linear (G21)
    const int sr = tid >> 3, ss = tid & 7;
    const int ssw = (ss ^ (sr & 7)) << 3;          // element offset of swizzled 16B slot
    const unsigned short* Kg = Kp + hb;
    const unsigned short* Vg = Vp + hb;

    // Q as B-operand: col=ln (q-row), k = ks*16 + hi*8 + i
    bf16x8 qf[4];
    {
        const unsigned short* qr = &Qp[hb + (size_t)(q0 + ln) * 64 + hi * 8];
#pragma unroll
        for (int ks = 0; ks < 4; ++ks) qf[ks] = ld16(qr + ks * 16);
    }

    f32x16 oacc0 = {}, oacc1 = {};
    float m = -1e30f, l = 0.f;

    auto stage = [&](int buf, int it) {
#pragma unroll
        for (int p = 0; p < 2; ++p) {
            __builtin_amdgcn_global_load_lds(
                (const __attribute__((address_space(1))) void*)&Kg[(size_t)(it*64 + p*32 + sr) * 64 + ssw],
                (__attribute__((address_space(3))) void*)&Ks[buf][p*2048 + tid*8], 16, 0, 0);
            __builtin_amdgcn_global_load_lds(
                (const __attribute__((address_space(1))) void*)&Vg[(size_t)(p*32 + sr) * 2048 + it*64 + ssw],
                (__attribute__((address_space(3))) void*)&Vs[buf][p*2048 + tid*8], 16, 0, 0);
        }
    };

    stage(0, 0);
    int cur = 0;

    for (int it = 0; it < 32; ++it) {
        __syncthreads();                 // implicit vmcnt(0): stage(cur) landed; buf !cur free
        stage(cur ^ 1, (it + 1) & 31);   // prefetch next tile under this iter's compute

        // fragments from LDS (conflict-free via XOR swizzle)
        bf16x8 kf[8], vf[8];
#pragma unroll
        for (int t2 = 0; t2 < 2; ++t2)
#pragma unroll
        for (int ks = 0; ks < 4; ++ks) {
            const int row = t2*32 + ln;
            const int sl  = ((ks*2 + hi) ^ (row & 7)) << 3;
            kf[t2*4+ks] = ld16(&Ks[cur][row*64 + sl]);
        }

        // S^T = K Q^T : lane holds 32 scores of q-row (q0+ln); kv = 32*tile + (r&3)+8*(r>>2)+4*hi
        f32x16 st0 = {}, st1 = {};
#pragma unroll
        for (int ks = 0; ks < 4; ++ks) {
            st0 = __builtin_amdgcn_mfma_f32_32x32x16_bf16(kf[ks],   qf[ks], st0, 0, 0, 0);
            st1 = __builtin_amdgcn_mfma_f32_32x32x16_bf16(kf[4+ks], qf[ks], st1, 0, 0, 0);
        }

#pragma unroll
        for (int t2 = 0; t2 < 2; ++t2)
#pragma unroll
        for (int ks = 0; ks < 4; ++ks) {
            const int row = t2*32 + ln;
            const int sl  = ((ks*2 + hi) ^ (row & 7)) << 3;
            vf[t2*4+ks] = ld16(&Vs[cur][row*64 + sl]);
        }

        // row max (lane-local tree + one xor-32)
        float mx[8];
#pragma unroll
        for (int r = 0; r < 8; ++r)
            mx[r] = fmaxf(fmaxf(st0[r], st0[r+8]), fmaxf(st1[r], st1[r+8]));
        float tm = fmaxf(fmaxf(fmaxf(mx[0],mx[1]), fmaxf(mx[2],mx[3])),
                         fmaxf(fmaxf(mx[4],mx[5]), fmaxf(mx[6],mx[7])));
        tm = fmaxf(tm, __shfl_xor(tm, 32, 64));
        // defer-max rescale (T13), log2 domain, THR=8 -> P <= 256
        if (__any(tm > m + 8.f)) {
            float mn = fmaxf(m, tm);
            float sc = fexp2(m - mn);
            m = mn;
            l *= sc;
            if (hi == 0) sml[w][ln] = sc;          // broadcast per-q-row scale
#pragma unroll
            for (int m4 = 0; m4 < 4; ++m4) {
                f32x4 sv = *reinterpret_cast<const f32x4*>(&sml[w][m4*8 + hi*4]);
#pragma unroll
                for (int r3 = 0; r3 < 4; ++r3) {
                    oacc0[m4*4+r3] *= sv[r3];
                    oacc1[m4*4+r3] *= sv[r3];
                }
            }
        }
        float p0a[16], p1a[16];
#pragma unroll
        for (int r = 0; r < 16; ++r) {
            p0a[r] = fexp2(st0[r] - m);
            p1a[r] = fexp2(st1[r] - m);
        }
        float s8[8];
#pragma unroll
        for (int r = 0; r < 8; ++r)
            s8[r] = (p0a[r] + p0a[r+8]) + (p1a[r] + p1a[r+8]);
        l += ((s8[0]+s8[1])+(s8[2]+s8[3])) + ((s8[4]+s8[5])+(s8[6]+s8[7]));

        // pack P -> bf16 pairs: Wp[m4][jj] = (kv 32t+8m4+4hi+2jj , +1)
        unsigned int Wp0[4][2], Wp1[4][2];
#pragma unroll
        for (int m4 = 0; m4 < 4; ++m4)
#pragma unroll
        for (int jj = 0; jj < 2; ++jj) {
            asm("v_cvt_pk_bf16_f32 %0, %1, %2" : "=v"(Wp0[m4][jj]) : "v"(p0a[m4*4+jj*2]), "v"(p0a[m4*4+jj*2+1]));
            asm("v_cvt_pk_bf16_f32 %0, %1, %2" : "=v"(Wp1[m4][jj]) : "v"(p1a[m4*4+jj*2]), "v"(p1a[m4*4+jj*2+1]));
        }
        // exchange the cross-half words (lane c <-> c+32)
        unsigned int Xp0[2][2], Xp1[2][2];
#pragma unroll
        for (int tp = 0; tp < 2; ++tp)
#pragma unroll
        for (int jj = 0; jj < 2; ++jj) {
            int s0 = hi ? (int)Wp0[2*tp][jj] : (int)Wp0[2*tp+1][jj];
            int s1 = hi ? (int)Wp1[2*tp][jj] : (int)Wp1[2*tp+1][jj];
            Xp0[tp][jj] = (unsigned int)__shfl_xor(s0, 32, 64);
            Xp1[tp][jj] = (unsigned int)__shfl_xor(s1, 32, 64);
        }
        // PV: A-frag(ks) = P[q=ln][kv = 16ks + 8hi + i]
#pragma unroll
        for (int ks = 0; ks < 4; ++ks) {
            const int tp = ks & 1;
            unsigned int A0, A1, B0, B1;
            if (ks < 2) {
                A0 = hi ? Wp0[2*tp+1][0] : Wp0[2*tp][0];
                A1 = hi ? Wp0[2*tp+1][1] : Wp0[2*tp][1];
                B0 = Xp0[tp][0]; B1 = Xp0[tp][1];
            } else {
                A0 = hi ? Wp1[2*tp+1][0] : Wp1[2*tp][0];
                A1 = hi ? Wp1[2*tp+1][1] : Wp1[2*tp][1];
                B0 = Xp1[tp][0]; B1 = Xp1[tp][1];
            }
            i32x4 pw;
            pw[0] = (int)(hi ? B0 : A0);
            pw[1] = (int)(hi ? B1 : A1);
            pw[2] = (int)(hi ? A0 : B0);
            pw[3] = (int)(hi ? A1 : B1);
            bf16x8 pf = __builtin_bit_cast(bf16x8, pw);
            oacc0 = __builtin_amdgcn_mfma_f32_32x32x16_bf16(pf, vf[ks],   oacc0, 0, 0, 0);
            oacc1 = __builtin_amdgcn_mfma_f32_32x32x16_bf16(pf, vf[4+ks], oacc1, 0, 0, 0);
        }
        cur ^= 1;
    }

    // epilogue: ctx = (1-a)*O/l + a*c
    float lf = l + __shfl_xor(l, 32, 64);
    if (hi == 0) sml[w][ln] = 1.0f / lf;
    const int b = bh >> 4, h = bh & 15;
    const float a1 = 1.f - alpha;
    const float cv0 = alpha * cvec[bh*64 + ln];
    const float cv1 = alpha * cvec[bh*64 + 32 + ln];
#pragma unroll
    for (int m4 = 0; m4 < 4; ++m4) {
        f32x4 iv = *reinterpret_cast<const f32x4*>(&sml[w][m4*8 + hi*4]);
#pragma unroll
        for (int r3 = 0; r3 < 4; ++r3) {
            const int row = m4*8 + hi*4 + r3;
            const int s = q0 + row;
            unsigned short* orow = &ctx[((size_t)(b*2048 + s))*1024 + h*64 + ln];
            orow[0]  = f2bf(a1 * oacc0[m4*4+r3] * iv[r3] + cv0);
            orow[32] = f2bf(a1 * oacc1[m4*4+r3] * iv[r3] + cv1);
        }
    }
}

// ---------------- launch ----------------
extern "C" void kernel_launch(void* const* d_in, const int* in_sizes, int n_in,
                              void* d_out, int out_size, void* d_ws, size_t ws_size,
                              hipStream_t stream) {
    const float* x     = (const float*)d_in[0];
    const float* ds    = (const float*)d_in[1];
    const float* q_w   = (const float*)d_in[2];
    const float* q_b   = (const float*)d_in[3];
    const float* k_w   = (const float*)d_in[4];
    const float* k_b   = (const float*)d_in[5];
    const float* v_w   = (const float*)d_in[6];
    const float* v_b   = (const float*)d_in[7];
    const float* o_w   = (const float*)d_in[8];
    const float* o_b   = (const float*)d_in[9];
    const float* alpha = (const float*)d_in[10];

    char* ws = (char*)d_ws;
    const size_t MB = 1024 * 1024;
    unsigned short* xb   = (unsigned short*)(ws);            // 8MB, reused as ctx
    unsigned short* wT   = (unsigned short*)(ws + 8  * MB);  // 8MB: wq|wk|wv|wo transposed bf16
    unsigned short* Qb   = (unsigned short*)(ws + 16 * MB);  // 8MB
    unsigned short* Kb   = (unsigned short*)(ws + 24 * MB);  // 8MB
    unsigned short* Vt   = (unsigned short*)(ws + 32 * MB);  // 8MB
    float*          cvec = (float*)         (ws + 40 * MB);  // 8KB
    unsigned short* ctxb = xb;

    const int M = 4096, K = 1024;

    cvt_x_kernel<<<2048, 256, 0, stream>>>(x, xb, M * K / 8);

    dim3 tb(32, 8);
    dim3 tg(32, 32, 4);
    tr_w_kernel<<<tg, tb, 0, stream>>>(q_w, k_w, v_w, o_w, wT);

    dim3 gqkv(24, 32);
    gemm_qkv<<<gqkv, 256, 0, stream>>>(xb, wT, q_b, k_b, v_b, Qb, Kb, Vt);

    hipMemsetAsync(cvec, 0, 32 * 64 * sizeof(float), stream);
    dock_c_kernel<<<256, 256, 0, stream>>>(ds, Vt, cvec);

    attn_kernel<<<512, 256, 0, stream>>>(Qb, Kb, Vt, cvec, alpha, ctxb);

    dim3 go(8, 32);
    gemm_o<<<go, 256, 0, stream>>>(ctxb, wT + (size_t)3 * MB, o_b, (float*)d_out);
}

// Round 4
// 150.222 us; speedup vs baseline: 3.1953x; 1.0891x over previous
//
#include <hip/hip_runtime.h>
#include <hip/hip_bf16.h>

typedef __attribute__((ext_vector_type(8)))  short bf16x8;
typedef __attribute__((ext_vector_type(4)))  float f32x4;
typedef __attribute__((ext_vector_type(16))) float f32x16;
typedef __attribute__((ext_vector_type(4)))  int   i32x4;
typedef __attribute__((ext_vector_type(4)))  unsigned short u16x4;
typedef __attribute__((ext_vector_type(8)))  unsigned short u16x8;

__device__ __forceinline__ unsigned short f2bf(float f) {
    unsigned int u = __builtin_bit_cast(unsigned int, f);
    u += 0x7FFFu + ((u >> 16) & 1u);   // RNE
    return (unsigned short)(u >> 16);
}
__device__ __forceinline__ float bf2f(unsigned short h) {
    unsigned int u = ((unsigned int)h) << 16;
    return __builtin_bit_cast(float, u);
}
__device__ __forceinline__ bf16x8 ld16(const unsigned short* p) {
    return *reinterpret_cast<const bf16x8*>(p);
}
__device__ __forceinline__ float fexp2(float x) {
    float r; asm("v_exp_f32 %0, %1" : "=v"(r) : "v"(x)); return r;
}

// ---------------- convert x (fp32 -> bf16), 8 elems/thread ----------------
__global__ void cvt_x_kernel(const float* __restrict__ in, unsigned short* __restrict__ out, int n8) {
    int idx = blockIdx.x * blockDim.x + threadIdx.x;
    int stride = gridDim.x * blockDim.x;
    for (int i = idx; i < n8; i += stride) {
        f32x4 a = reinterpret_cast<const f32x4*>(in)[i*2];
        f32x4 b = reinterpret_cast<const f32x4*>(in)[i*2+1];
        u16x8 o;
        o[0]=f2bf(a[0]); o[1]=f2bf(a[1]); o[2]=f2bf(a[2]); o[3]=f2bf(a[3]);
        o[4]=f2bf(b[0]); o[5]=f2bf(b[1]); o[6]=f2bf(b[2]); o[7]=f2bf(b[3]);
        reinterpret_cast<u16x8*>(out)[i] = o;
    }
}

// ---------------- transpose+convert all 4 weights: W(K,N) fp32 -> WT(N,K) bf16 ----------------
__global__ void tr_w_kernel(const float* __restrict__ q_w, const float* __restrict__ k_w,
                            const float* __restrict__ v_w, const float* __restrict__ o_w,
                            unsigned short* __restrict__ WT) {
    __shared__ float tile[32][33];
    const float* W = (blockIdx.z == 0) ? q_w : (blockIdx.z == 1) ? k_w : (blockIdx.z == 2) ? v_w : o_w;
    unsigned short* dst = WT + (size_t)blockIdx.z * 1024 * 1024;
    int tx = threadIdx.x, ty = threadIdx.y;         // (32,8)
    int n0 = blockIdx.x * 32, k0 = blockIdx.y * 32;
#pragma unroll
    for (int j = 0; j < 4; ++j)
        tile[ty + j*8][tx] = W[(size_t)(k0 + ty + j*8) * 1024 + n0 + tx];
    __syncthreads();
#pragma unroll
    for (int j = 0; j < 4; ++j)
        dst[(size_t)(n0 + ty + j*8) * 1024 + k0 + tx] = f2bf(tile[tx][ty + j*8]);
}

// ---------------- merged QKV GEMM: [Q|K|V] = x * [wq|wk|wv]^T, m97-style gload_lds staging ----------------
__global__ __launch_bounds__(256) void gemm_qkv(
    const unsigned short* __restrict__ A,     // (4096,1024) bf16
    const unsigned short* __restrict__ WT,    // (3072,1024) bf16
    const float* __restrict__ qb, const float* __restrict__ kbias, const float* __restrict__ vbias,
    unsigned short* __restrict__ Qo, unsigned short* __restrict__ Ko, unsigned short* __restrict__ Vto)
{
    __shared__ __align__(16) unsigned short As[128*64];
    __shared__ __align__(16) unsigned short Bs[128*64];
    const int tid = threadIdx.x, lane = tid & 63, w = tid >> 6;
    const int wm = w >> 1, wn = w & 1;
    const int m0 = blockIdx.y * 128, n0 = blockIdx.x * 128;   // grid (24,32)
    const int K = 1024;
    f32x4 acc[4][4] = {};
    for (int k0 = 0; k0 < K; k0 += 64) {
#pragma unroll
        for (int j = 0; j < 4; ++j) {
            const int c = j*256 + tid, r = c >> 3, s = c & 7;
            __builtin_amdgcn_global_load_lds(
                (const __attribute__((address_space(1))) void*)&A[(size_t)(m0+r)*K + k0 + s*8],
                (__attribute__((address_space(3))) void*)&As[(size_t)c*8], 16, 0, 0);
            __builtin_amdgcn_global_load_lds(
                (const __attribute__((address_space(1))) void*)&WT[(size_t)(n0+r)*K + k0 + s*8],
                (__attribute__((address_space(3))) void*)&Bs[(size_t)c*8], 16, 0, 0);
        }
        __syncthreads();
#pragma unroll
        for (int kc = 0; kc < 2; ++kc) {
            bf16x8 af[4], bfr[4];
            const int slog = kc*4 + (lane >> 4);
#pragma unroll
            for (int t = 0; t < 4; ++t) {
                const int row = wm*64 + t*16 + (lane & 15);
                af[t]  = ld16(&As[row*64 + slog*8]);
                const int col = wn*64 + t*16 + (lane & 15);
                bfr[t] = ld16(&Bs[col*64 + slog*8]);
            }
#pragma unroll
            for (int mt = 0; mt < 4; ++mt)
#pragma unroll
                for (int nt = 0; nt < 4; ++nt)
                    acc[mt][nt] = __builtin_amdgcn_mfma_f32_16x16x32_bf16(af[mt], bfr[nt], acc[mt][nt], 0, 0, 0);
        }
        __syncthreads();
    }
    const int mat = n0 >> 10;
    if (mat == 2) {
        // V -> Vt (B,H,64,S)
#pragma unroll
        for (int mt = 0; mt < 4; ++mt)
#pragma unroll
        for (int nt = 0; nt < 4; ++nt) {
            const int nl = (n0 & 1023) + wn*64 + nt*16 + (lane & 15);
            const int h = nl >> 6, hd = nl & 63;
            const int mbase = m0 + wm*64 + mt*16 + ((lane >> 4) << 2);
            const int b = mbase >> 11, s = mbase & 2047;
            const float bv = vbias[nl];
            u16x4 pk;
#pragma unroll
            for (int r = 0; r < 4; ++r) pk[r] = f2bf(acc[mt][nt][r] + bv);
            *reinterpret_cast<u16x4*>(&Vto[((size_t)((b << 4) | h) * 64 + hd) * 2048 + s]) = pk;
        }
    } else {
        unsigned short* outp = mat ? Ko : Qo;
        const float* bias = mat ? kbias : qb;
        // Q: fold 1/sqrt(64) * log2(e) so attention works in exp2 domain
        const float scale = mat ? 1.0f : 0.180336881f;
#pragma unroll
        for (int mt = 0; mt < 4; ++mt)
#pragma unroll
        for (int nt = 0; nt < 4; ++nt) {
            const int nl = (n0 & 1023) + wn*64 + nt*16 + (lane & 15);
            const int h = nl >> 6, hd = nl & 63;
            const int mbase = m0 + wm*64 + mt*16 + ((lane >> 4) << 2);
            const float bv = bias[nl];
#pragma unroll
            for (int r = 0; r < 4; ++r) {
                const int mm2 = mbase + r, b = mm2 >> 11, s = mm2 & 2047;
                outp[((size_t)((b << 4) | h) * 2048 + s) * 64 + hd] = f2bf((acc[mt][nt][r] + bv) * scale);
            }
        }
    }
}

// ---------------- O projection GEMM: fp32 out ----------------
__global__ __launch_bounds__(256) void gemm_o(
    const unsigned short* __restrict__ A, const unsigned short* __restrict__ WT,
    const float* __restrict__ bias, float* __restrict__ Cout)
{
    __shared__ __align__(16) unsigned short As[128*64];
    __shared__ __align__(16) unsigned short Bs[128*64];
    const int tid = threadIdx.x, lane = tid & 63, w = tid >> 6;
    const int wm = w >> 1, wn = w & 1;
    const int m0 = blockIdx.y * 128, n0 = blockIdx.x * 128;   // grid (8,32)
    const int K = 1024;
    f32x4 acc[4][4] = {};
    for (int k0 = 0; k0 < K; k0 += 64) {
#pragma unroll
        for (int j = 0; j < 4; ++j) {
            const int c = j*256 + tid, r = c >> 3, s = c & 7;
            __builtin_amdgcn_global_load_lds(
                (const __attribute__((address_space(1))) void*)&A[(size_t)(m0+r)*K + k0 + s*8],
                (__attribute__((address_space(3))) void*)&As[(size_t)c*8], 16, 0, 0);
            __builtin_amdgcn_global_load_lds(
                (const __attribute__((address_space(1))) void*)&WT[(size_t)(n0+r)*K + k0 + s*8],
                (__attribute__((address_space(3))) void*)&Bs[(size_t)c*8], 16, 0, 0);
        }
        __syncthreads();
#pragma unroll
        for (int kc = 0; kc < 2; ++kc) {
            bf16x8 af[4], bfr[4];
            const int slog = kc*4 + (lane >> 4);
#pragma unroll
            for (int t = 0; t < 4; ++t) {
                const int row = wm*64 + t*16 + (lane & 15);
                af[t]  = ld16(&As[row*64 + slog*8]);
                const int col = wn*64 + t*16 + (lane & 15);
                bfr[t] = ld16(&Bs[col*64 + slog*8]);
            }
#pragma unroll
            for (int mt = 0; mt < 4; ++mt)
#pragma unroll
                for (int nt = 0; nt < 4; ++nt)
                    acc[mt][nt] = __builtin_amdgcn_mfma_f32_16x16x32_bf16(af[mt], bfr[nt], acc[mt][nt], 0, 0, 0);
        }
        __syncthreads();
    }
#pragma unroll
    for (int mt = 0; mt < 4; ++mt)
#pragma unroll
    for (int nt = 0; nt < 4; ++nt) {
        const int n = n0 + wn*64 + nt*16 + (lane & 15);
        const int mbase = m0 + wm*64 + mt*16 + ((lane >> 4) << 2);
        const float bv = bias[n];
#pragma unroll
        for (int r = 0; r < 4; ++r)
            Cout[(size_t)(mbase + r) * 1024 + n] = acc[mt][nt][r] + bv;
    }
}

// ---------------- c[b,h,d] = sum_k ds[b,k] * V[b,h,k,d]  (reads Vt), 256 blocks + atomics ----------------
__global__ void dock_c_kernel(const float* __restrict__ ds, const unsigned short* __restrict__ Vt,
                              float* __restrict__ cvec) {
    __shared__ float red[256];
    const int bh = blockIdx.x >> 3, sl = blockIdx.x & 7;
    const int b = bh >> 4;
    const int t = threadIdx.x, d = t & 63, q4 = t >> 6;
    const unsigned short* vrow = &Vt[(size_t)bh * 131072 + (size_t)d * 2048 + sl * 256 + q4 * 64];
    const float* dsr = &ds[b * 2048 + sl * 256 + q4 * 64];
    float sum = 0.f;
#pragma unroll
    for (int k = 0; k < 64; k += 8) {
        bf16x8 v = ld16(&vrow[k]);
#pragma unroll
        for (int i = 0; i < 8; ++i) sum += dsr[k + i] * bf2f((unsigned short)v[i]);
    }
    red[t] = sum;
    __syncthreads();
    if (t < 64) atomicAdd(&cvec[bh * 64 + t], red[t] + red[64 + t] + red[128 + t] + red[192 + t]);
}

// ---------------- flash attention: LDS-staged K/V, pipelined QK(t+1) || softmax(t) ----------------
__global__ __launch_bounds__(256, 2) void attn_kernel(
    const unsigned short* __restrict__ Qp,   // (BH,S,64), pre-scaled by 0.125*log2e
    const unsigned short* __restrict__ Kp,   // (BH,S,64)
    const unsigned short* __restrict__ Vp,   // (BH,64,S)
    const float* __restrict__ cvec,          // (BH,64)
    const float* __restrict__ alpha_p,
    unsigned short* __restrict__ ctx)        // (B,S,1024)
{
    __shared__ __align__(16) unsigned short Ks[2][4096];   // 2 x 8KB: 64 kv x 64 d, swizzled
    __shared__ __align__(16) unsigned short Vs[2][4096];   // 2 x 8KB: 64 hd x 64 kv, swizzled
    __shared__ float sml[4][32];
    const int tid = threadIdx.x, lane = tid & 63, w = tid >> 6;
    const int hi = lane >> 5, ln = lane & 31;
    // XCD-aware swizzle: 512 blocks = 8 XCDs x 64; each XCD owns 4 contiguous heads
    const int wg = blockIdx.x;
    const int swz = (wg & 7) * 64 + (wg >> 3);
    const int bh = swz >> 4, qt = swz & 15;
    const int q0 = qt * 128 + w * 32;                        // 32 q-rows per wave
    const size_t hb = (size_t)bh * (2048 * 64);
    const float alpha = *alpha_p;

    // staging geometry: thread -> (row sr, slot ss); source slot pre-swizzled, LDS dest linear (G21)
    const int sr = tid >> 3, ss = tid & 7;
    const int ssw = (ss ^ (sr & 7)) << 3;          // element offset of swizzled 16B slot
    const unsigned short* Kg = Kp + hb;
    const unsigned short* Vg = Vp + hb;

    // Q as B-operand: col=ln (q-row), k = ks*16 + hi*8 + i
    bf16x8 qf[4];
    {
        const unsigned short* qr = &Qp[hb + (size_t)(q0 + ln) * 64 + hi * 8];
#pragma unroll
        for (int ks = 0; ks < 4; ++ks) qf[ks] = ld16(qr + ks * 16);
    }

    f32x16 oacc0 = {}, oacc1 = {};
    float m = -1e30f, l = 0.f;

    auto stage = [&](int buf, int it) {
#pragma unroll
        for (int p = 0; p < 2; ++p) {
            __builtin_amdgcn_global_load_lds(
                (const __attribute__((address_space(1))) void*)&Kg[(size_t)(it*64 + p*32 + sr) * 64 + ssw],
                (__attribute__((address_space(3))) void*)&Ks[buf][p*2048 + tid*8], 16, 0, 0);
            __builtin_amdgcn_global_load_lds(
                (const __attribute__((address_space(1))) void*)&Vg[(size_t)(p*32 + sr) * 2048 + it*64 + ssw],
                (__attribute__((address_space(3))) void*)&Vs[buf][p*2048 + tid*8], 16, 0, 0);
        }
    };

    bf16x8 kf[8];
    auto ldk = [&](const unsigned short* base) {
#pragma unroll
        for (int t2 = 0; t2 < 2; ++t2)
#pragma unroll
        for (int ks = 0; ks < 4; ++ks) {
            const int row = t2*32 + ln;
            const int sl  = ((ks*2 + hi) ^ (row & 7)) << 3;
            kf[t2*4+ks] = ld16(base + row*64 + sl);
        }
    };

    // prologue: stage tiles 0,1; compute QK(0) -> sA
    stage(0, 0);
    __syncthreads();
    stage(1, 1);
    ldk(&Ks[0][0]);
    f32x16 sA0 = {}, sA1 = {}, sB0 = {}, sB1 = {};
#pragma unroll
    for (int ks = 0; ks < 4; ++ks) {
        sA0 = __builtin_amdgcn_mfma_f32_32x32x16_bf16(kf[ks],   qf[ks], sA0, 0, 0, 0);
        sA1 = __builtin_amdgcn_mfma_f32_32x32x16_bf16(kf[4+ks], qf[ks], sA1, 0, 0, 0);
    }

    // step: consume scores sc (tile it, in buffer `buf`), produce sn = QK(it+1)
    auto step = [&](f32x16& sc0, f32x16& sc1, f32x16& sn0, f32x16& sn1, int buf, int it) {
        // V(it) from LDS -- must complete before the barrier below
        bf16x8 vf[8];
#pragma unroll
        for (int t2 = 0; t2 < 2; ++t2)
#pragma unroll
        for (int ks = 0; ks < 4; ++ks) {
            const int row = t2*32 + ln;
            const int sl  = ((ks*2 + hi) ^ (row & 7)) << 3;
            vf[t2*4+ks] = ld16(&Vs[buf][row*64 + sl]);
        }
        __syncthreads();                 // stage(it+1) landed; all waves done reading tile it
        if (it + 2 < 32) stage(buf, it + 2);   // overwrite consumed buffer
        const bool more = (it + 1 < 32);
        if (more) ldk(&Ks[buf ^ 1][0]);
        __builtin_amdgcn_s_setprio(1);
        if (more) {
            sn0 = {}; sn1 = {};
#pragma unroll
            for (int ks = 0; ks < 4; ++ks) {
                sn0 = __builtin_amdgcn_mfma_f32_32x32x16_bf16(kf[ks],   qf[ks], sn0, 0, 0, 0);
                sn1 = __builtin_amdgcn_mfma_f32_32x32x16_bf16(kf[4+ks], qf[ks], sn1, 0, 0, 0);
            }
        }
        // ---- softmax on sc (independent of QK above -> co-issues on VALU/trans) ----
        float mx[8];
#pragma unroll
        for (int r = 0; r < 8; ++r)
            mx[r] = fmaxf(fmaxf(sc0[r], sc0[r+8]), fmaxf(sc1[r], sc1[r+8]));
        float tm = fmaxf(fmaxf(fmaxf(mx[0],mx[1]), fmaxf(mx[2],mx[3])),
                         fmaxf(fmaxf(mx[4],mx[5]), fmaxf(mx[6],mx[7])));
        tm = fmaxf(tm, __shfl_xor(tm, 32, 64));
        if (__any(tm > m + 8.f)) {       // defer-max (T13), log2 domain
            float mn = fmaxf(m, tm);
            float sc = fexp2(m - mn);
            m = mn;
            l *= sc;
            if (hi == 0) sml[w][ln] = sc;
#pragma unroll
            for (int m4 = 0; m4 < 4; ++m4) {
                f32x4 sv = *reinterpret_cast<const f32x4*>(&sml[w][m4*8 + hi*4]);
#pragma unroll
                for (int r3 = 0; r3 < 4; ++r3) {
                    oacc0[m4*4+r3] *= sv[r3];
                    oacc1[m4*4+r3] *= sv[r3];
                }
            }
        }
        float p0a[16], p1a[16];
#pragma unroll
        for (int r = 0; r < 16; ++r) {
            p0a[r] = fexp2(sc0[r] - m);
            p1a[r] = fexp2(sc1[r] - m);
        }
        float s8[8];
#pragma unroll
        for (int r = 0; r < 8; ++r)
            s8[r] = (p0a[r] + p0a[r+8]) + (p1a[r] + p1a[r+8]);
        l += ((s8[0]+s8[1])+(s8[2]+s8[3])) + ((s8[4]+s8[5])+(s8[6]+s8[7]));

        unsigned int Wp0[4][2], Wp1[4][2];
#pragma unroll
        for (int m4 = 0; m4 < 4; ++m4)
#pragma unroll
        for (int jj = 0; jj < 2; ++jj) {
            asm("v_cvt_pk_bf16_f32 %0, %1, %2" : "=v"(Wp0[m4][jj]) : "v"(p0a[m4*4+jj*2]), "v"(p0a[m4*4+jj*2+1]));
            asm("v_cvt_pk_bf16_f32 %0, %1, %2" : "=v"(Wp1[m4][jj]) : "v"(p1a[m4*4+jj*2]), "v"(p1a[m4*4+jj*2+1]));
        }
        unsigned int Xp0[2][2], Xp1[2][2];
#pragma unroll
        for (int tp = 0; tp < 2; ++tp)
#pragma unroll
        for (int jj = 0; jj < 2; ++jj) {
            int s0 = hi ? (int)Wp0[2*tp][jj] : (int)Wp0[2*tp+1][jj];
            int s1 = hi ? (int)Wp1[2*tp][jj] : (int)Wp1[2*tp+1][jj];
            Xp0[tp][jj] = (unsigned int)__shfl_xor(s0, 32, 64);
            Xp1[tp][jj] = (unsigned int)__shfl_xor(s1, 32, 64);
        }
        // ---- PV ----
#pragma unroll
        for (int ks = 0; ks < 4; ++ks) {
            const int tp = ks & 1;
            unsigned int A0, A1, B0, B1;
            if (ks < 2) {
                A0 = hi ? Wp0[2*tp+1][0] : Wp0[2*tp][0];
                A1 = hi ? Wp0[2*tp+1][1] : Wp0[2*tp][1];
                B0 = Xp0[tp][0]; B1 = Xp0[tp][1];
            } else {
                A0 = hi ? Wp1[2*tp+1][0] : Wp1[2*tp][0];
                A1 = hi ? Wp1[2*tp+1][1] : Wp1[2*tp][1];
                B0 = Xp1[tp][0]; B1 = Xp1[tp][1];
            }
            i32x4 pw;
            pw[0] = (int)(hi ? B0 : A0);
            pw[1] = (int)(hi ? B1 : A1);
            pw[2] = (int)(hi ? A0 : B0);
            pw[3] = (int)(hi ? A1 : B1);
            bf16x8 pf = __builtin_bit_cast(bf16x8, pw);
            oacc0 = __builtin_amdgcn_mfma_f32_32x32x16_bf16(pf, vf[ks],   oacc0, 0, 0, 0);
            oacc1 = __builtin_amdgcn_mfma_f32_32x32x16_bf16(pf, vf[4+ks], oacc1, 0, 0, 0);
        }
        __builtin_amdgcn_s_setprio(0);
    };

#pragma unroll 1
    for (int ii = 0; ii < 16; ++ii) {
        step(sA0, sA1, sB0, sB1, 0, ii*2);
        step(sB0, sB1, sA0, sA1, 1, ii*2 + 1);
    }

    // epilogue: ctx = (1-a)*O/l + a*c
    float lf = l + __shfl_xor(l, 32, 64);
    if (hi == 0) sml[w][ln] = 1.0f / lf;
    const int b = bh >> 4, h = bh & 15;
    const float a1 = 1.f - alpha;
    const float cv0 = alpha * cvec[bh*64 + ln];
    const float cv1 = alpha * cvec[bh*64 + 32 + ln];
#pragma unroll
    for (int m4 = 0; m4 < 4; ++m4) {
        f32x4 iv = *reinterpret_cast<const f32x4*>(&sml[w][m4*8 + hi*4]);
#pragma unroll
        for (int r3 = 0; r3 < 4; ++r3) {
            const int row = m4*8 + hi*4 + r3;
            const int s = q0 + row;
            unsigned short* orow = &ctx[((size_t)(b*2048 + s))*1024 + h*64 + ln];
            orow[0]  = f2bf(a1 * oacc0[m4*4+r3] * iv[r3] + cv0);
            orow[32] = f2bf(a1 * oacc1[m4*4+r3] * iv[r3] + cv1);
        }
    }
}

// ---------------- launch ----------------
extern "C" void kernel_launch(void* const* d_in, const int* in_sizes, int n_in,
                              void* d_out, int out_size, void* d_ws, size_t ws_size,
                              hipStream_t stream) {
    const float* x     = (const float*)d_in[0];
    const float* ds    = (const float*)d_in[1];
    const float* q_w   = (const float*)d_in[2];
    const float* q_b   = (const float*)d_in[3];
    const float* k_w   = (const float*)d_in[4];
    const float* k_b   = (const float*)d_in[5];
    const float* v_w   = (const float*)d_in[6];
    const float* v_b   = (const float*)d_in[7];
    const float* o_w   = (const float*)d_in[8];
    const float* o_b   = (const float*)d_in[9];
    const float* alpha = (const float*)d_in[10];

    char* ws = (char*)d_ws;
    const size_t MB = 1024 * 1024;
    unsigned short* xb   = (unsigned short*)(ws);            // 8MB, reused as ctx
    unsigned short* wT   = (unsigned short*)(ws + 8  * MB);  // 8MB: wq|wk|wv|wo transposed bf16
    unsigned short* Qb   = (unsigned short*)(ws + 16 * MB);  // 8MB
    unsigned short* Kb   = (unsigned short*)(ws + 24 * MB);  // 8MB
    unsigned short* Vt   = (unsigned short*)(ws + 32 * MB);  // 8MB
    float*          cvec = (float*)         (ws + 40 * MB);  // 8KB
    unsigned short* ctxb = xb;

    const int M = 4096, K = 1024;

    cvt_x_kernel<<<2048, 256, 0, stream>>>(x, xb, M * K / 8);

    dim3 tb(32, 8);
    dim3 tg(32, 32, 4);
    tr_w_kernel<<<tg, tb, 0, stream>>>(q_w, k_w, v_w, o_w, wT);

    dim3 gqkv(24, 32);
    gemm_qkv<<<gqkv, 256, 0, stream>>>(xb, wT, q_b, k_b, v_b, Qb, Kb, Vt);

    hipMemsetAsync(cvec, 0, 32 * 64 * sizeof(float), stream);
    dock_c_kernel<<<256, 256, 0, stream>>>(ds, Vt, cvec);

    attn_kernel<<<512, 256, 0, stream>>>(Qb, Kb, Vt, cvec, alpha, ctxb);

    dim3 go(8, 32);
    gemm_o<<<go, 256, 0, stream>>>(ctxb, wT + (size_t)3 * MB, o_b, (float*)d_out);
}

// Round 5
// 144.861 us; speedup vs baseline: 3.3135x; 1.0370x over previous
//
#include <hip/hip_runtime.h>
#include <hip/hip_bf16.h>

typedef __attribute__((ext_vector_type(8)))  short bf16x8;
typedef __attribute__((ext_vector_type(4)))  float f32x4;
typedef __attribute__((ext_vector_type(16))) float f32x16;
typedef __attribute__((ext_vector_type(4)))  int   i32x4;
typedef __attribute__((ext_vector_type(4)))  unsigned short u16x4;
typedef __attribute__((ext_vector_type(8)))  unsigned short u16x8;

__device__ __forceinline__ unsigned short f2bf(float f) {
    unsigned int u = __builtin_bit_cast(unsigned int, f);
    u += 0x7FFFu + ((u >> 16) & 1u);   // RNE
    return (unsigned short)(u >> 16);
}
__device__ __forceinline__ float bf2f(unsigned short h) {
    unsigned int u = ((unsigned int)h) << 16;
    return __builtin_bit_cast(float, u);
}
__device__ __forceinline__ bf16x8 ld16(const unsigned short* p) {
    return *reinterpret_cast<const bf16x8*>(p);
}
__device__ __forceinline__ float fexp2(float x) {
    float r; asm("v_exp_f32 %0, %1" : "=v"(r) : "v"(x)); return r;
}
__device__ __forceinline__ float frcp(float x) {
    float r; asm("v_rcp_f32 %0, %1" : "=v"(r) : "v"(x)); return r;
}
// gfx950: swap a.hi32lanes <-> b.lo32lanes. After: a={a_lo,b_lo}, b={a_hi,b_hi}
__device__ __forceinline__ void pswap(unsigned int& a, unsigned int& b) {
    asm("v_permlane32_swap_b32 %0, %1" : "+v"(a), "+v"(b));
}

// ---------------- convert x (fp32 -> bf16), 8 elems/thread ----------------
__global__ void cvt_x_kernel(const float* __restrict__ in, unsigned short* __restrict__ out, int n8) {
    int idx = blockIdx.x * blockDim.x + threadIdx.x;
    int stride = gridDim.x * blockDim.x;
    for (int i = idx; i < n8; i += stride) {
        f32x4 a = reinterpret_cast<const f32x4*>(in)[i*2];
        f32x4 b = reinterpret_cast<const f32x4*>(in)[i*2+1];
        u16x8 o;
        o[0]=f2bf(a[0]); o[1]=f2bf(a[1]); o[2]=f2bf(a[2]); o[3]=f2bf(a[3]);
        o[4]=f2bf(b[0]); o[5]=f2bf(b[1]); o[6]=f2bf(b[2]); o[7]=f2bf(b[3]);
        reinterpret_cast<u16x8*>(out)[i] = o;
    }
}

// ---------------- transpose+convert all 4 weights: W(K,N) fp32 -> WT(N,K) bf16 ----------------
__global__ void tr_w_kernel(const float* __restrict__ q_w, const float* __restrict__ k_w,
                            const float* __restrict__ v_w, const float* __restrict__ o_w,
                            unsigned short* __restrict__ WT) {
    __shared__ float tile[32][33];
    const float* W = (blockIdx.z == 0) ? q_w : (blockIdx.z == 1) ? k_w : (blockIdx.z == 2) ? v_w : o_w;
    unsigned short* dst = WT + (size_t)blockIdx.z * 1024 * 1024;
    int tx = threadIdx.x, ty = threadIdx.y;         // (32,8)
    int n0 = blockIdx.x * 32, k0 = blockIdx.y * 32;
#pragma unroll
    for (int j = 0; j < 4; ++j)
        tile[ty + j*8][tx] = W[(size_t)(k0 + ty + j*8) * 1024 + n0 + tx];
    __syncthreads();
#pragma unroll
    for (int j = 0; j < 4; ++j)
        dst[(size_t)(n0 + ty + j*8) * 1024 + k0 + tx] = f2bf(tile[tx][ty + j*8]);
}

// ---------------- merged QKV GEMM: [Q|K|V] = x * [wq|wk|wv]^T, m97-style gload_lds staging ----------------
__global__ __launch_bounds__(256) void gemm_qkv(
    const unsigned short* __restrict__ A,     // (4096,1024) bf16
    const unsigned short* __restrict__ WT,    // (3072,1024) bf16
    const float* __restrict__ qb, const float* __restrict__ kbias, const float* __restrict__ vbias,
    unsigned short* __restrict__ Qo, unsigned short* __restrict__ Ko, unsigned short* __restrict__ Vto)
{
    __shared__ __align__(16) unsigned short As[128*64];
    __shared__ __align__(16) unsigned short Bs[128*64];
    const int tid = threadIdx.x, lane = tid & 63, w = tid >> 6;
    const int wm = w >> 1, wn = w & 1;
    const int m0 = blockIdx.y * 128, n0 = blockIdx.x * 128;   // grid (24,32)
    const int K = 1024;
    f32x4 acc[4][4] = {};
    for (int k0 = 0; k0 < K; k0 += 64) {
#pragma unroll
        for (int j = 0; j < 4; ++j) {
            const int c = j*256 + tid, r = c >> 3, s = c & 7;
            __builtin_amdgcn_global_load_lds(
                (const __attribute__((address_space(1))) void*)&A[(size_t)(m0+r)*K + k0 + s*8],
                (__attribute__((address_space(3))) void*)&As[(size_t)c*8], 16, 0, 0);
            __builtin_amdgcn_global_load_lds(
                (const __attribute__((address_space(1))) void*)&WT[(size_t)(n0+r)*K + k0 + s*8],
                (__attribute__((address_space(3))) void*)&Bs[(size_t)c*8], 16, 0, 0);
        }
        __syncthreads();
#pragma unroll
        for (int kc = 0; kc < 2; ++kc) {
            bf16x8 af[4], bfr[4];
            const int slog = kc*4 + (lane >> 4);
#pragma unroll
            for (int t = 0; t < 4; ++t) {
                const int row = wm*64 + t*16 + (lane & 15);
                af[t]  = ld16(&As[row*64 + slog*8]);
                const int col = wn*64 + t*16 + (lane & 15);
                bfr[t] = ld16(&Bs[col*64 + slog*8]);
            }
#pragma unroll
            for (int mt = 0; mt < 4; ++mt)
#pragma unroll
                for (int nt = 0; nt < 4; ++nt)
                    acc[mt][nt] = __builtin_amdgcn_mfma_f32_16x16x32_bf16(af[mt], bfr[nt], acc[mt][nt], 0, 0, 0);
        }
        __syncthreads();
    }
    const int mat = n0 >> 10;
    if (mat == 2) {
        // V -> Vt (B,H,64,S)
#pragma unroll
        for (int mt = 0; mt < 4; ++mt)
#pragma unroll
        for (int nt = 0; nt < 4; ++nt) {
            const int nl = (n0 & 1023) + wn*64 + nt*16 + (lane & 15);
            const int h = nl >> 6, hd = nl & 63;
            const int mbase = m0 + wm*64 + mt*16 + ((lane >> 4) << 2);
            const int b = mbase >> 11, s = mbase & 2047;
            const float bv = vbias[nl];
            u16x4 pk;
#pragma unroll
            for (int r = 0; r < 4; ++r) pk[r] = f2bf(acc[mt][nt][r] + bv);
            *reinterpret_cast<u16x4*>(&Vto[((size_t)((b << 4) | h) * 64 + hd) * 2048 + s]) = pk;
        }
    } else {
        unsigned short* outp = mat ? Ko : Qo;
        const float* bias = mat ? kbias : qb;
        // Q: fold 1/sqrt(64) * log2(e) so attention works in exp2 domain
        const float scale = mat ? 1.0f : 0.180336881f;
#pragma unroll
        for (int mt = 0; mt < 4; ++mt)
#pragma unroll
        for (int nt = 0; nt < 4; ++nt) {
            const int nl = (n0 & 1023) + wn*64 + nt*16 + (lane & 15);
            const int h = nl >> 6, hd = nl & 63;
            const int mbase = m0 + wm*64 + mt*16 + ((lane >> 4) << 2);
            const float bv = bias[nl];
#pragma unroll
            for (int r = 0; r < 4; ++r) {
                const int mm2 = mbase + r, b = mm2 >> 11, s = mm2 & 2047;
                outp[((size_t)((b << 4) | h) * 2048 + s) * 64 + hd] = f2bf((acc[mt][nt][r] + bv) * scale);
            }
        }
    }
}

// ---------------- O projection GEMM: fp32 out ----------------
__global__ __launch_bounds__(256) void gemm_o(
    const unsigned short* __restrict__ A, const unsigned short* __restrict__ WT,
    const float* __restrict__ bias, float* __restrict__ Cout)
{
    __shared__ __align__(16) unsigned short As[128*64];
    __shared__ __align__(16) unsigned short Bs[128*64];
    const int tid = threadIdx.x, lane = tid & 63, w = tid >> 6;
    const int wm = w >> 1, wn = w & 1;
    const int m0 = blockIdx.y * 128, n0 = blockIdx.x * 128;   // grid (8,32)
    const int K = 1024;
    f32x4 acc[4][4] = {};
    for (int k0 = 0; k0 < K; k0 += 64) {
#pragma unroll
        for (int j = 0; j < 4; ++j) {
            const int c = j*256 + tid, r = c >> 3, s = c & 7;
            __builtin_amdgcn_global_load_lds(
                (const __attribute__((address_space(1))) void*)&A[(size_t)(m0+r)*K + k0 + s*8],
                (__attribute__((address_space(3))) void*)&As[(size_t)c*8], 16, 0, 0);
            __builtin_amdgcn_global_load_lds(
                (const __attribute__((address_space(1))) void*)&WT[(size_t)(n0+r)*K + k0 + s*8],
                (__attribute__((address_space(3))) void*)&Bs[(size_t)c*8], 16, 0, 0);
        }
        __syncthreads();
#pragma unroll
        for (int kc = 0; kc < 2; ++kc) {
            bf16x8 af[4], bfr[4];
            const int slog = kc*4 + (lane >> 4);
#pragma unroll
            for (int t = 0; t < 4; ++t) {
                const int row = wm*64 + t*16 + (lane & 15);
                af[t]  = ld16(&As[row*64 + slog*8]);
                const int col = wn*64 + t*16 + (lane & 15);
                bfr[t] = ld16(&Bs[col*64 + slog*8]);
            }
#pragma unroll
            for (int mt = 0; mt < 4; ++mt)
#pragma unroll
                for (int nt = 0; nt < 4; ++nt)
                    acc[mt][nt] = __builtin_amdgcn_mfma_f32_16x16x32_bf16(af[mt], bfr[nt], acc[mt][nt], 0, 0, 0);
        }
        __syncthreads();
    }
#pragma unroll
    for (int mt = 0; mt < 4; ++mt)
#pragma unroll
    for (int nt = 0; nt < 4; ++nt) {
        const int n = n0 + wn*64 + nt*16 + (lane & 15);
        const int mbase = m0 + wm*64 + mt*16 + ((lane >> 4) << 2);
        const float bv = bias[n];
#pragma unroll
        for (int r = 0; r < 4; ++r)
            Cout[(size_t)(mbase + r) * 1024 + n] = acc[mt][nt][r] + bv;
    }
}

// ---------------- c[b,h,d] = sum_k ds[b,k] * V[b,h,k,d]  (reads Vt), 256 blocks + atomics ----------------
__global__ void dock_c_kernel(const float* __restrict__ ds, const unsigned short* __restrict__ Vt,
                              float* __restrict__ cvec) {
    __shared__ float red[256];
    const int bh = blockIdx.x >> 3, sl = blockIdx.x & 7;
    const int b = bh >> 4;
    const int t = threadIdx.x, d = t & 63, q4 = t >> 6;
    const unsigned short* vrow = &Vt[(size_t)bh * 131072 + (size_t)d * 2048 + sl * 256 + q4 * 64];
    const float* dsr = &ds[b * 2048 + sl * 256 + q4 * 64];
    float sum = 0.f;
#pragma unroll
    for (int k = 0; k < 64; k += 8) {
        bf16x8 v = ld16(&vrow[k]);
#pragma unroll
        for (int i = 0; i < 8; ++i) sum += dsr[k + i] * bf2f((unsigned short)v[i]);
    }
    red[t] = sum;
    __syncthreads();
    if (t < 64) atomicAdd(&cvec[bh * 64 + t], red[t] + red[64 + t] + red[128 + t] + red[192 + t]);
}

// ---------------- flash attention: LDS-staged K/V, pipelined QK(t+1) || softmax(t) ----------------
__global__ __launch_bounds__(256, 2) void attn_kernel(
    const unsigned short* __restrict__ Qp,   // (BH,S,64), pre-scaled by 0.125*log2e
    const unsigned short* __restrict__ Kp,   // (BH,S,64)
    const unsigned short* __restrict__ Vp,   // (BH,64,S)
    const float* __restrict__ cvec,          // (BH,64)
    const float* __restrict__ alpha_p,
    unsigned short* __restrict__ ctx)        // (B,S,1024)
{
    __shared__ __align__(16) unsigned short Ks[2][4096];   // 2 x 8KB: 64 kv x 64 d, swizzled
    __shared__ __align__(16) unsigned short Vs[2][4096];   // 2 x 8KB: 64 hd x 64 kv, swizzled
    __shared__ float sml[4][32];
    const int tid = threadIdx.x, lane = tid & 63, w = tid >> 6;
    const int hi = lane >> 5, ln = lane & 31;
    // XCD-aware swizzle: 512 blocks = 8 XCDs x 64; each XCD owns 4 contiguous heads
    const int wg = blockIdx.x;
    const int swz = (wg & 7) * 64 + (wg >> 3);
    const int bh = swz >> 4, qt = swz & 15;
    const int q0 = qt * 128 + w * 32;                        // 32 q-rows per wave
    const size_t hb = (size_t)bh * (2048 * 64);
    const float alpha = *alpha_p;

    // staging geometry: thread -> (row sr, slot ss); source slot pre-swizzled, LDS dest linear (G21)
    const int sr = tid >> 3, ss = tid & 7;
    const int ssw = (ss ^ (sr & 7)) << 3;          // element offset of swizzled 16B slot
    const unsigned short* Kg = Kp + hb;
    const unsigned short* Vg = Vp + hb;

    // Q as B-operand: col=ln (q-row), k = ks*16 + hi*8 + i
    bf16x8 qf[4];
    {
        const unsigned short* qr = &Qp[hb + (size_t)(q0 + ln) * 64 + hi * 8];
#pragma unroll
        for (int ks = 0; ks < 4; ++ks) qf[ks] = ld16(qr + ks * 16);
    }

    // ones B-fragment for MFMA row-sum of P
    const short one_bf = (short)0x3F80;
    const bf16x8 onesf = {one_bf, one_bf, one_bf, one_bf, one_bf, one_bf, one_bf, one_bf};

    f32x16 oacc0 = {}, oacc1 = {}, lacc = {};
    float m = -1e30f;

    auto stage = [&](int buf, int it) {
#pragma unroll
        for (int p = 0; p < 2; ++p) {
            __builtin_amdgcn_global_load_lds(
                (const __attribute__((address_space(1))) void*)&Kg[(size_t)(it*64 + p*32 + sr) * 64 + ssw],
                (__attribute__((address_space(3))) void*)&Ks[buf][p*2048 + tid*8], 16, 0, 0);
            __builtin_amdgcn_global_load_lds(
                (const __attribute__((address_space(1))) void*)&Vg[(size_t)(p*32 + sr) * 2048 + it*64 + ssw],
                (__attribute__((address_space(3))) void*)&Vs[buf][p*2048 + tid*8], 16, 0, 0);
        }
    };

    bf16x8 kf[8];
    auto ldk = [&](const unsigned short* base) {
#pragma unroll
        for (int t2 = 0; t2 < 2; ++t2)
#pragma unroll
        for (int ks = 0; ks < 4; ++ks) {
            const int row = t2*32 + ln;
            const int sl  = ((ks*2 + hi) ^ (row & 7)) << 3;
            kf[t2*4+ks] = ld16(base + row*64 + sl);
        }
    };

    // prologue: stage tiles 0,1; compute QK(0) -> sA
    stage(0, 0);
    __syncthreads();
    stage(1, 1);
    ldk(&Ks[0][0]);
    f32x16 sA0 = {}, sA1 = {}, sB0 = {}, sB1 = {};
#pragma unroll
    for (int ks = 0; ks < 4; ++ks) {
        sA0 = __builtin_amdgcn_mfma_f32_32x32x16_bf16(kf[ks],   qf[ks], sA0, 0, 0, 0);
        sA1 = __builtin_amdgcn_mfma_f32_32x32x16_bf16(kf[4+ks], qf[ks], sA1, 0, 0, 0);
    }

    // step: consume scores sc (tile it, in buffer `buf`), produce sn = QK(it+1)
    auto step = [&](f32x16& sc0, f32x16& sc1, f32x16& sn0, f32x16& sn1, int buf, int it) {
        // V(it) from LDS -- must complete before the barrier below
        bf16x8 vf[8];
#pragma unroll
        for (int t2 = 0; t2 < 2; ++t2)
#pragma unroll
        for (int ks = 0; ks < 4; ++ks) {
            const int row = t2*32 + ln;
            const int sl  = ((ks*2 + hi) ^ (row & 7)) << 3;
            vf[t2*4+ks] = ld16(&Vs[buf][row*64 + sl]);
        }
        __syncthreads();                 // stage(it+1) landed; all waves done reading tile it
        if (it + 2 < 32) stage(buf, it + 2);   // overwrite consumed buffer
        const bool more = (it + 1 < 32);
        if (more) ldk(&Ks[buf ^ 1][0]);
        __builtin_amdgcn_s_setprio(1);
        if (more) {
            sn0 = {}; sn1 = {};
#pragma unroll
            for (int ks = 0; ks < 4; ++ks) {
                sn0 = __builtin_amdgcn_mfma_f32_32x32x16_bf16(kf[ks],   qf[ks], sn0, 0, 0, 0);
                sn1 = __builtin_amdgcn_mfma_f32_32x32x16_bf16(kf[4+ks], qf[ks], sn1, 0, 0, 0);
            }
        }
        // ---- softmax on sc (independent of QK above -> co-issues on VALU/trans) ----
        float mx[8];
#pragma unroll
        for (int r = 0; r < 8; ++r)
            mx[r] = fmaxf(fmaxf(sc0[r], sc0[r+8]), fmaxf(sc1[r], sc1[r+8]));
        float tm = fmaxf(fmaxf(fmaxf(mx[0],mx[1]), fmaxf(mx[2],mx[3])),
                         fmaxf(fmaxf(mx[4],mx[5]), fmaxf(mx[6],mx[7])));
        {   // cross-32 max via permlane (no DS-pipe shuffle on the critical path)
            unsigned int ua = __builtin_bit_cast(unsigned int, tm), ub = ua;
            pswap(ua, ub);   // ua[l] = tm[l&31], ub[l] = tm[32|(l&31)]
            tm = fmaxf(__builtin_bit_cast(float, ua), __builtin_bit_cast(float, ub));
        }
        if (__any(tm > m + 8.f)) {       // defer-max (T13), log2 domain
            float mn = fmaxf(m, tm);
            float sc = fexp2(m - mn);
            m = mn;
            if (hi == 0) sml[w][ln] = sc;
#pragma unroll
            for (int m4 = 0; m4 < 4; ++m4) {
                f32x4 sv = *reinterpret_cast<const f32x4*>(&sml[w][m4*8 + hi*4]);
#pragma unroll
                for (int r3 = 0; r3 < 4; ++r3) {
                    oacc0[m4*4+r3] *= sv[r3];
                    oacc1[m4*4+r3] *= sv[r3];
                    lacc [m4*4+r3] *= sv[r3];
                }
            }
        }
        float p0a[16], p1a[16];
#pragma unroll
        for (int r = 0; r < 16; ++r) {
            p0a[r] = fexp2(sc0[r] - m);
            p1a[r] = fexp2(sc1[r] - m);
        }

        // pack P -> bf16 pairs: Wp[m4][jj] = (kv 32t+8m4+4hi+2jj , +1)
        unsigned int Wp0[4][2], Wp1[4][2];
#pragma unroll
        for (int m4 = 0; m4 < 4; ++m4)
#pragma unroll
        for (int jj = 0; jj < 2; ++jj) {
            asm("v_cvt_pk_bf16_f32 %0, %1, %2" : "=v"(Wp0[m4][jj]) : "v"(p0a[m4*4+jj*2]), "v"(p0a[m4*4+jj*2+1]));
            asm("v_cvt_pk_bf16_f32 %0, %1, %2" : "=v"(Wp1[m4][jj]) : "v"(p1a[m4*4+jj*2]), "v"(p1a[m4*4+jj*2+1]));
        }
        // ---- PV + MFMA row-sum; C->A relayout via permlane32_swap (zero selects) ----
#pragma unroll
        for (int ks = 0; ks < 4; ++ks) {
            const int tp = ks & 1;
            unsigned int a0, a1, b0, b1;
            if (ks < 2) { a0 = Wp0[2*tp][0]; a1 = Wp0[2*tp][1]; b0 = Wp0[2*tp+1][0]; b1 = Wp0[2*tp+1][1]; }
            else        { a0 = Wp1[2*tp][0]; a1 = Wp1[2*tp][1]; b0 = Wp1[2*tp+1][0]; b1 = Wp1[2*tp+1][1]; }
            pswap(a0, b0);   // a={a_lo,b_lo} -> k 0..3 words; b={a_hi,b_hi} -> k 4..7 words
            pswap(a1, b1);
            i32x4 pw;
            pw[0] = (int)a0; pw[1] = (int)a1; pw[2] = (int)b0; pw[3] = (int)b1;
            bf16x8 pf = __builtin_bit_cast(bf16x8, pw);
            oacc0 = __builtin_amdgcn_mfma_f32_32x32x16_bf16(pf, vf[ks],   oacc0, 0, 0, 0);
            oacc1 = __builtin_amdgcn_mfma_f32_32x32x16_bf16(pf, vf[4+ks], oacc1, 0, 0, 0);
            lacc  = __builtin_amdgcn_mfma_f32_32x32x16_bf16(pf, onesf,    lacc,  0, 0, 0);
        }
        __builtin_amdgcn_s_setprio(0);
    };

#pragma unroll 1
    for (int ii = 0; ii < 16; ++ii) {
        step(sA0, sA1, sB0, sB1, 0, ii*2);
        step(sB0, sB1, sA0, sA1, 1, ii*2 + 1);
    }

    // epilogue: ctx = (1-a)*O/l + a*c   (lacc rows = q, all cols equal -> direct 1/l)
    const int b = bh >> 4, h = bh & 15;
    const float a1f = 1.f - alpha;
    const float cv0 = alpha * cvec[bh*64 + ln];
    const float cv1 = alpha * cvec[bh*64 + 32 + ln];
#pragma unroll
    for (int m4 = 0; m4 < 4; ++m4) {
#pragma unroll
        for (int r3 = 0; r3 < 4; ++r3) {
            const int row = m4*8 + hi*4 + r3;
            const int s = q0 + row;
            const float iv = frcp(lacc[m4*4 + r3]);
            unsigned short* orow = &ctx[((size_t)(b*2048 + s))*1024 + h*64 + ln];
            orow[0]  = f2bf(a1f * oacc0[m4*4+r3] * iv + cv0);
            orow[32] = f2bf(a1f * oacc1[m4*4+r3] * iv + cv1);
        }
    }
}

// ---------------- launch ----------------
extern "C" void kernel_launch(void* const* d_in, const int* in_sizes, int n_in,
                              void* d_out, int out_size, void* d_ws, size_t ws_size,
                              hipStream_t stream) {
    const float* x     = (const float*)d_in[0];
    const float* ds    = (const float*)d_in[1];
    const float* q_w   = (const float*)d_in[2];
    const float* q_b   = (const float*)d_in[3];
    const float* k_w   = (const float*)d_in[4];
    const float* k_b   = (const float*)d_in[5];
    const float* v_w   = (const float*)d_in[6];
    const float* v_b   = (const float*)d_in[7];
    const float* o_w   = (const float*)d_in[8];
    const float* o_b   = (const float*)d_in[9];
    const float* alpha = (const float*)d_in[10];

    char* ws = (char*)d_ws;
    const size_t MB = 1024 * 1024;
    unsigned short* xb   = (unsigned short*)(ws);            // 8MB, reused as ctx
    unsigned short* wT   = (unsigned short*)(ws + 8  * MB);  // 8MB: wq|wk|wv|wo transposed bf16
    unsigned short* Qb   = (unsigned short*)(ws + 16 * MB);  // 8MB
    unsigned short* Kb   = (unsigned short*)(ws + 24 * MB);  // 8MB
    unsigned short* Vt   = (unsigned short*)(ws + 32 * MB);  // 8MB
    float*          cvec = (float*)         (ws + 40 * MB);  // 8KB
    unsigned short* ctxb = xb;

    const int M = 4096, K = 1024;

    cvt_x_kernel<<<2048, 256, 0, stream>>>(x, xb, M * K / 8);

    dim3 tb(32, 8);
    dim3 tg(32, 32, 4);
    tr_w_kernel<<<tg, tb, 0, stream>>>(q_w, k_w, v_w, o_w, wT);

    dim3 gqkv(24, 32);
    gemm_qkv<<<gqkv, 256, 0, stream>>>(xb, wT, q_b, k_b, v_b, Qb, Kb, Vt);

    hipMemsetAsync(cvec, 0, 32 * 64 * sizeof(float), stream);
    dock_c_kernel<<<256, 256, 0, stream>>>(ds, Vt, cvec);

    attn_kernel<<<512, 256, 0, stream>>>(Qb, Kb, Vt, cvec, alpha, ctxb);

    dim3 go(8, 32);
    gemm_o<<<go, 256, 0, stream>>>(ctxb, wT + (size_t)3 * MB, o_b, (float*)d_out);
}

// Round 6
// 127.721 us; speedup vs baseline: 3.7582x; 1.1342x over previous
//
#include <hip/hip_runtime.h>
#include <hip/hip_bf16.h>

typedef __attribute__((ext_vector_type(8)))  short bf16x8;
typedef __attribute__((ext_vector_type(4)))  float f32x4;
typedef __attribute__((ext_vector_type(16))) float f32x16;
typedef __attribute__((ext_vector_type(4)))  int   i32x4;
typedef __attribute__((ext_vector_type(4)))  unsigned short u16x4;
typedef __attribute__((ext_vector_type(8)))  unsigned short u16x8;

__device__ __forceinline__ unsigned short f2bf(float f) {
    unsigned int u = __builtin_bit_cast(unsigned int, f);
    u += 0x7FFFu + ((u >> 16) & 1u);   // RNE
    return (unsigned short)(u >> 16);
}
__device__ __forceinline__ float bf2f(unsigned short h) {
    unsigned int u = ((unsigned int)h) << 16;
    return __builtin_bit_cast(float, u);
}
__device__ __forceinline__ bf16x8 ld16(const unsigned short* p) {
    return *reinterpret_cast<const bf16x8*>(p);
}
__device__ __forceinline__ float fexp2(float x) {
    float r; asm("v_exp_f32 %0, %1" : "=v"(r) : "v"(x)); return r;
}
__device__ __forceinline__ float frcp(float x) {
    float r; asm("v_rcp_f32 %0, %1" : "=v"(r) : "v"(x)); return r;
}
// gfx950: swap a.hi32lanes <-> b.lo32lanes. After: a={a_lo,b_lo}, b={a_hi,b_hi}
__device__ __forceinline__ void pswap(unsigned int& a, unsigned int& b) {
    asm("v_permlane32_swap_b32 %0, %1" : "+v"(a), "+v"(b));
}

// ---------------- convert x (fp32 -> bf16), 8 elems/thread ----------------
__global__ void cvt_x_kernel(const float* __restrict__ in, unsigned short* __restrict__ out, int n8) {
    int idx = blockIdx.x * blockDim.x + threadIdx.x;
    int stride = gridDim.x * blockDim.x;
    for (int i = idx; i < n8; i += stride) {
        f32x4 a = reinterpret_cast<const f32x4*>(in)[i*2];
        f32x4 b = reinterpret_cast<const f32x4*>(in)[i*2+1];
        u16x8 o;
        o[0]=f2bf(a[0]); o[1]=f2bf(a[1]); o[2]=f2bf(a[2]); o[3]=f2bf(a[3]);
        o[4]=f2bf(b[0]); o[5]=f2bf(b[1]); o[6]=f2bf(b[2]); o[7]=f2bf(b[3]);
        reinterpret_cast<u16x8*>(out)[i] = o;
    }
}

// ---------------- transpose+convert all 4 weights: W(K,N) fp32 -> WT(N,K) bf16 ----------------
__global__ void tr_w_kernel(const float* __restrict__ q_w, const float* __restrict__ k_w,
                            const float* __restrict__ v_w, const float* __restrict__ o_w,
                            unsigned short* __restrict__ WT) {
    __shared__ float tile[32][33];
    const float* W = (blockIdx.z == 0) ? q_w : (blockIdx.z == 1) ? k_w : (blockIdx.z == 2) ? v_w : o_w;
    unsigned short* dst = WT + (size_t)blockIdx.z * 1024 * 1024;
    int tx = threadIdx.x, ty = threadIdx.y;         // (32,8)
    int n0 = blockIdx.x * 32, k0 = blockIdx.y * 32;
#pragma unroll
    for (int j = 0; j < 4; ++j)
        tile[ty + j*8][tx] = W[(size_t)(k0 + ty + j*8) * 1024 + n0 + tx];
    __syncthreads();
#pragma unroll
    for (int j = 0; j < 4; ++j)
        dst[(size_t)(n0 + ty + j*8) * 1024 + k0 + tx] = f2bf(tile[tx][ty + j*8]);
}

// ---------------- merged QKV GEMM: swizzled LDS (T2/G21) + dbuf prefetch ----------------
__global__ __launch_bounds__(256) void gemm_qkv(
    const unsigned short* __restrict__ A,     // (4096,1024) bf16
    const unsigned short* __restrict__ WT,    // (3072,1024) bf16
    const float* __restrict__ qb, const float* __restrict__ kbias, const float* __restrict__ vbias,
    unsigned short* __restrict__ Qo, unsigned short* __restrict__ Ko, unsigned short* __restrict__ Vto)
{
    __shared__ __align__(16) unsigned short As[2][128*64];
    __shared__ __align__(16) unsigned short Bs[2][128*64];
    const int tid = threadIdx.x, lane = tid & 63, w = tid >> 6;
    const int wm = w >> 1, wn = w & 1;
    const int m0 = blockIdx.y * 128, n0 = blockIdx.x * 128;   // grid (24,32)
    const int K = 1024;
    // staging: thread covers rows j*32+sr, slot ssl; source slot pre-swizzled, LDS linear (G21)
    const int sr = tid >> 3, ssl = tid & 7;
    const int ssw = (ssl ^ (sr & 7)) << 3;
    f32x4 acc[4][4] = {};

    auto stage = [&](int buf, int k0) {
#pragma unroll
        for (int j = 0; j < 4; ++j) {
            const int c = j*256 + tid, r = j*32 + sr;
            __builtin_amdgcn_global_load_lds(
                (const __attribute__((address_space(1))) void*)&A[(size_t)(m0+r)*K + k0 + ssw],
                (__attribute__((address_space(3))) void*)&As[buf][(size_t)c*8], 16, 0, 0);
            __builtin_amdgcn_global_load_lds(
                (const __attribute__((address_space(1))) void*)&WT[(size_t)(n0+r)*K + k0 + ssw],
                (__attribute__((address_space(3))) void*)&Bs[buf][(size_t)c*8], 16, 0, 0);
        }
    };

    stage(0, 0);
#pragma unroll 1
    for (int t = 0; t < 16; ++t) {
        __syncthreads();                       // implicit vmcnt(0): buf[t&1] landed; buf[t^1] free
        if (t < 15) stage((t + 1) & 1, (t + 1) * 64);
        const unsigned short* pa = &As[t & 1][0];
        const unsigned short* pb = &Bs[t & 1][0];
#pragma unroll
        for (int kc = 0; kc < 2; ++kc) {
            bf16x8 af[4], bfr[4];
            const int slog = kc*4 + (lane >> 4);
#pragma unroll
            for (int t2 = 0; t2 < 4; ++t2) {
                const int row = wm*64 + t2*16 + (lane & 15);
                af[t2]  = ld16(&pa[row*64 + ((slog ^ (row & 7)) << 3)]);
                const int col = wn*64 + t2*16 + (lane & 15);
                bfr[t2] = ld16(&pb[col*64 + ((slog ^ (col & 7)) << 3)]);
            }
#pragma unroll
            for (int mt = 0; mt < 4; ++mt)
#pragma unroll
                for (int nt = 0; nt < 4; ++nt)
                    acc[mt][nt] = __builtin_amdgcn_mfma_f32_16x16x32_bf16(af[mt], bfr[nt], acc[mt][nt], 0, 0, 0);
        }
    }
    const int mat = n0 >> 10;
    if (mat == 2) {
        // V -> Vt (B,H,64,S)
#pragma unroll
        for (int mt = 0; mt < 4; ++mt)
#pragma unroll
        for (int nt = 0; nt < 4; ++nt) {
            const int nl = (n0 & 1023) + wn*64 + nt*16 + (lane & 15);
            const int h = nl >> 6, hd = nl & 63;
            const int mbase = m0 + wm*64 + mt*16 + ((lane >> 4) << 2);
            const int b = mbase >> 11, s = mbase & 2047;
            const float bv = vbias[nl];
            u16x4 pk;
#pragma unroll
            for (int r = 0; r < 4; ++r) pk[r] = f2bf(acc[mt][nt][r] + bv);
            *reinterpret_cast<u16x4*>(&Vto[((size_t)((b << 4) | h) * 64 + hd) * 2048 + s]) = pk;
        }
    } else {
        unsigned short* outp = mat ? Ko : Qo;
        const float* bias = mat ? kbias : qb;
        // Q: fold 1/sqrt(64) * log2(e) so attention works in exp2 domain
        const float scale = mat ? 1.0f : 0.180336881f;
#pragma unroll
        for (int mt = 0; mt < 4; ++mt)
#pragma unroll
        for (int nt = 0; nt < 4; ++nt) {
            const int nl = (n0 & 1023) + wn*64 + nt*16 + (lane & 15);
            const int h = nl >> 6, hd = nl & 63;
            const int mbase = m0 + wm*64 + mt*16 + ((lane >> 4) << 2);
            const float bv = bias[nl];
#pragma unroll
            for (int r = 0; r < 4; ++r) {
                const int mm2 = mbase + r, b = mm2 >> 11, s = mm2 & 2047;
                outp[((size_t)((b << 4) | h) * 2048 + s) * 64 + hd] = f2bf((acc[mt][nt][r] + bv) * scale);
            }
        }
    }
}

// ---------------- O projection GEMM: fp32 out, same swizzle+dbuf ----------------
__global__ __launch_bounds__(256) void gemm_o(
    const unsigned short* __restrict__ A, const unsigned short* __restrict__ WT,
    const float* __restrict__ bias, float* __restrict__ Cout)
{
    __shared__ __align__(16) unsigned short As[2][128*64];
    __shared__ __align__(16) unsigned short Bs[2][128*64];
    const int tid = threadIdx.x, lane = tid & 63, w = tid >> 6;
    const int wm = w >> 1, wn = w & 1;
    const int m0 = blockIdx.y * 128, n0 = blockIdx.x * 128;   // grid (8,32)
    const int K = 1024;
    const int sr = tid >> 3, ssl = tid & 7;
    const int ssw = (ssl ^ (sr & 7)) << 3;
    f32x4 acc[4][4] = {};

    auto stage = [&](int buf, int k0) {
#pragma unroll
        for (int j = 0; j < 4; ++j) {
            const int c = j*256 + tid, r = j*32 + sr;
            __builtin_amdgcn_global_load_lds(
                (const __attribute__((address_space(1))) void*)&A[(size_t)(m0+r)*K + k0 + ssw],
                (__attribute__((address_space(3))) void*)&As[buf][(size_t)c*8], 16, 0, 0);
            __builtin_amdgcn_global_load_lds(
                (const __attribute__((address_space(1))) void*)&WT[(size_t)(n0+r)*K + k0 + ssw],
                (__attribute__((address_space(3))) void*)&Bs[buf][(size_t)c*8], 16, 0, 0);
        }
    };

    stage(0, 0);
#pragma unroll 1
    for (int t = 0; t < 16; ++t) {
        __syncthreads();
        if (t < 15) stage((t + 1) & 1, (t + 1) * 64);
        const unsigned short* pa = &As[t & 1][0];
        const unsigned short* pb = &Bs[t & 1][0];
#pragma unroll
        for (int kc = 0; kc < 2; ++kc) {
            bf16x8 af[4], bfr[4];
            const int slog = kc*4 + (lane >> 4);
#pragma unroll
            for (int t2 = 0; t2 < 4; ++t2) {
                const int row = wm*64 + t2*16 + (lane & 15);
                af[t2]  = ld16(&pa[row*64 + ((slog ^ (row & 7)) << 3)]);
                const int col = wn*64 + t2*16 + (lane & 15);
                bfr[t2] = ld16(&pb[col*64 + ((slog ^ (col & 7)) << 3)]);
            }
#pragma unroll
            for (int mt = 0; mt < 4; ++mt)
#pragma unroll
                for (int nt = 0; nt < 4; ++nt)
                    acc[mt][nt] = __builtin_amdgcn_mfma_f32_16x16x32_bf16(af[mt], bfr[nt], acc[mt][nt], 0, 0, 0);
        }
    }
#pragma unroll
    for (int mt = 0; mt < 4; ++mt)
#pragma unroll
    for (int nt = 0; nt < 4; ++nt) {
        const int n = n0 + wn*64 + nt*16 + (lane & 15);
        const int mbase = m0 + wm*64 + mt*16 + ((lane >> 4) << 2);
        const float bv = bias[n];
#pragma unroll
        for (int r = 0; r < 4; ++r)
            Cout[(size_t)(mbase + r) * 1024 + n] = acc[mt][nt][r] + bv;
    }
}

// ---------------- c[b,h,d] = sum_k ds[b,k] * V[b,h,k,d]  (reads Vt), 256 blocks + atomics ----------------
__global__ void dock_c_kernel(const float* __restrict__ ds, const unsigned short* __restrict__ Vt,
                              float* __restrict__ cvec) {
    __shared__ float red[256];
    const int bh = blockIdx.x >> 3, sl = blockIdx.x & 7;
    const int b = bh >> 4;
    const int t = threadIdx.x, d = t & 63, q4 = t >> 6;
    const unsigned short* vrow = &Vt[(size_t)bh * 131072 + (size_t)d * 2048 + sl * 256 + q4 * 64];
    const float* dsr = &ds[b * 2048 + sl * 256 + q4 * 64];
    float sum = 0.f;
#pragma unroll
    for (int k = 0; k < 64; k += 8) {
        bf16x8 v = ld16(&vrow[k]);
#pragma unroll
        for (int i = 0; i < 8; ++i) sum += dsr[k + i] * bf2f((unsigned short)v[i]);
    }
    red[t] = sum;
    __syncthreads();
    if (t < 64) atomicAdd(&cvec[bh * 64 + t], red[t] + red[64 + t] + red[128 + t] + red[192 + t]);
}

// ---------------- flash attention: LDS-staged K/V, pipelined QK(t+1) || softmax(t) ----------------
__global__ __launch_bounds__(256, 2) void attn_kernel(
    const unsigned short* __restrict__ Qp,   // (BH,S,64), pre-scaled by 0.125*log2e
    const unsigned short* __restrict__ Kp,   // (BH,S,64)
    const unsigned short* __restrict__ Vp,   // (BH,64,S)
    const float* __restrict__ cvec,          // (BH,64)
    const float* __restrict__ alpha_p,
    unsigned short* __restrict__ ctx)        // (B,S,1024)
{
    __shared__ __align__(16) unsigned short Ks[2][4096];   // 2 x 8KB: 64 kv x 64 d, swizzled
    __shared__ __align__(16) unsigned short Vs[2][4096];   // 2 x 8KB: 64 hd x 64 kv, swizzled
    __shared__ float sml[4][32];
    const int tid = threadIdx.x, lane = tid & 63, w = tid >> 6;
    const int hi = lane >> 5, ln = lane & 31;
    // XCD-aware swizzle: 512 blocks = 8 XCDs x 64; each XCD owns 4 contiguous heads
    const int wg = blockIdx.x;
    const int swz = (wg & 7) * 64 + (wg >> 3);
    const int bh = swz >> 4, qt = swz & 15;
    const int q0 = qt * 128 + w * 32;                        // 32 q-rows per wave
    const size_t hb = (size_t)bh * (2048 * 64);
    const float alpha = *alpha_p;

    // staging geometry: thread -> (row sr, slot ss); source slot pre-swizzled, LDS dest linear (G21)
    const int sr = tid >> 3, ss = tid & 7;
    const int ssw = (ss ^ (sr & 7)) << 3;          // element offset of swizzled 16B slot
    const unsigned short* Kg = Kp + hb;
    const unsigned short* Vg = Vp + hb;

    // Q as B-operand: col=ln (q-row), k = ks*16 + hi*8 + i
    bf16x8 qf[4];
    {
        const unsigned short* qr = &Qp[hb + (size_t)(q0 + ln) * 64 + hi * 8];
#pragma unroll
        for (int ks = 0; ks < 4; ++ks) qf[ks] = ld16(qr + ks * 16);
    }

    // ones B-fragment for MFMA row-sum of P
    const short one_bf = (short)0x3F80;
    const bf16x8 onesf = {one_bf, one_bf, one_bf, one_bf, one_bf, one_bf, one_bf, one_bf};

    f32x16 oacc0 = {}, oacc1 = {}, lacc = {};
    float m = -1e30f;

    auto stage = [&](int buf, int it) {
#pragma unroll
        for (int p = 0; p < 2; ++p) {
            __builtin_amdgcn_global_load_lds(
                (const __attribute__((address_space(1))) void*)&Kg[(size_t)(it*64 + p*32 + sr) * 64 + ssw],
                (__attribute__((address_space(3))) void*)&Ks[buf][p*2048 + tid*8], 16, 0, 0);
            __builtin_amdgcn_global_load_lds(
                (const __attribute__((address_space(1))) void*)&Vg[(size_t)(p*32 + sr) * 2048 + it*64 + ssw],
                (__attribute__((address_space(3))) void*)&Vs[buf][p*2048 + tid*8], 16, 0, 0);
        }
    };

    bf16x8 kf[8];
    auto ldk = [&](const unsigned short* base) {
#pragma unroll
        for (int t2 = 0; t2 < 2; ++t2)
#pragma unroll
        for (int ks = 0; ks < 4; ++ks) {
            const int row = t2*32 + ln;
            const int sl  = ((ks*2 + hi) ^ (row & 7)) << 3;
            kf[t2*4+ks] = ld16(base + row*64 + sl);
        }
    };

    // prologue: stage tiles 0,1; compute QK(0) -> sA
    stage(0, 0);
    __syncthreads();
    stage(1, 1);
    ldk(&Ks[0][0]);
    f32x16 sA0 = {}, sA1 = {}, sB0 = {}, sB1 = {};
#pragma unroll
    for (int ks = 0; ks < 4; ++ks) {
        sA0 = __builtin_amdgcn_mfma_f32_32x32x16_bf16(kf[ks],   qf[ks], sA0, 0, 0, 0);
        sA1 = __builtin_amdgcn_mfma_f32_32x32x16_bf16(kf[4+ks], qf[ks], sA1, 0, 0, 0);
    }

    // step: consume scores sc (tile it, in buffer `buf`), produce sn = QK(it+1)
    auto step = [&](f32x16& sc0, f32x16& sc1, f32x16& sn0, f32x16& sn1, int buf, int it) {
        // V(it) from LDS -- must complete before the barrier below
        bf16x8 vf[8];
#pragma unroll
        for (int t2 = 0; t2 < 2; ++t2)
#pragma unroll
        for (int ks = 0; ks < 4; ++ks) {
            const int row = t2*32 + ln;
            const int sl  = ((ks*2 + hi) ^ (row & 7)) << 3;
            vf[t2*4+ks] = ld16(&Vs[buf][row*64 + sl]);
        }
        __syncthreads();                 // stage(it+1) landed; all waves done reading tile it
        if (it + 2 < 32) stage(buf, it + 2);   // overwrite consumed buffer
        const bool more = (it + 1 < 32);
        if (more) ldk(&Ks[buf ^ 1][0]);
        __builtin_amdgcn_s_setprio(1);
        if (more) {
            sn0 = {}; sn1 = {};
#pragma unroll
            for (int ks = 0; ks < 4; ++ks) {
                sn0 = __builtin_amdgcn_mfma_f32_32x32x16_bf16(kf[ks],   qf[ks], sn0, 0, 0, 0);
                sn1 = __builtin_amdgcn_mfma_f32_32x32x16_bf16(kf[4+ks], qf[ks], sn1, 0, 0, 0);
            }
        }
        // ---- softmax on sc (independent of QK above -> co-issues on VALU/trans) ----
        float mx[8];
#pragma unroll
        for (int r = 0; r < 8; ++r)
            mx[r] = fmaxf(fmaxf(sc0[r], sc0[r+8]), fmaxf(sc1[r], sc1[r+8]));
        float tm = fmaxf(fmaxf(fmaxf(mx[0],mx[1]), fmaxf(mx[2],mx[3])),
                         fmaxf(fmaxf(mx[4],mx[5]), fmaxf(mx[6],mx[7])));
        {   // cross-32 max via permlane (no DS-pipe shuffle on the critical path)
            unsigned int ua = __builtin_bit_cast(unsigned int, tm), ub = ua;
            pswap(ua, ub);   // ua[l] = tm[l&31], ub[l] = tm[32|(l&31)]
            tm = fmaxf(__builtin_bit_cast(float, ua), __builtin_bit_cast(float, ub));
        }
        if (__any(tm > m + 8.f)) {       // defer-max (T13), log2 domain
            float mn = fmaxf(m, tm);
            float sc = fexp2(m - mn);
            m = mn;
            if (hi == 0) sml[w][ln] = sc;
#pragma unroll
            for (int m4 = 0; m4 < 4; ++m4) {
                f32x4 sv = *reinterpret_cast<const f32x4*>(&sml[w][m4*8 + hi*4]);
#pragma unroll
                for (int r3 = 0; r3 < 4; ++r3) {
                    oacc0[m4*4+r3] *= sv[r3];
                    oacc1[m4*4+r3] *= sv[r3];
                    lacc [m4*4+r3] *= sv[r3];
                }
            }
        }
        float p0a[16], p1a[16];
#pragma unroll
        for (int r = 0; r < 16; ++r) {
            p0a[r] = fexp2(sc0[r] - m);
            p1a[r] = fexp2(sc1[r] - m);
        }

        // pack P -> bf16 pairs: Wp[m4][jj] = (kv 32t+8m4+4hi+2jj , +1)
        unsigned int Wp0[4][2], Wp1[4][2];
#pragma unroll
        for (int m4 = 0; m4 < 4; ++m4)
#pragma unroll
        for (int jj = 0; jj < 2; ++jj) {
            asm("v_cvt_pk_bf16_f32 %0, %1, %2" : "=v"(Wp0[m4][jj]) : "v"(p0a[m4*4+jj*2]), "v"(p0a[m4*4+jj*2+1]));
            asm("v_cvt_pk_bf16_f32 %0, %1, %2" : "=v"(Wp1[m4][jj]) : "v"(p1a[m4*4+jj*2]), "v"(p1a[m4*4+jj*2+1]));
        }
        // ---- PV + MFMA row-sum; C->A relayout via permlane32_swap (zero selects) ----
#pragma unroll
        for (int ks = 0; ks < 4; ++ks) {
            const int tp = ks & 1;
            unsigned int a0, a1, b0, b1;
            if (ks < 2) { a0 = Wp0[2*tp][0]; a1 = Wp0[2*tp][1]; b0 = Wp0[2*tp+1][0]; b1 = Wp0[2*tp+1][1]; }
            else        { a0 = Wp1[2*tp][0]; a1 = Wp1[2*tp][1]; b0 = Wp1[2*tp+1][0]; b1 = Wp1[2*tp+1][1]; }
            pswap(a0, b0);   // a={a_lo,b_lo} -> k 0..3 words; b={a_hi,b_hi} -> k 4..7 words
            pswap(a1, b1);
            i32x4 pw;
            pw[0] = (int)a0; pw[1] = (int)a1; pw[2] = (int)b0; pw[3] = (int)b1;
            bf16x8 pf = __builtin_bit_cast(bf16x8, pw);
            oacc0 = __builtin_amdgcn_mfma_f32_32x32x16_bf16(pf, vf[ks],   oacc0, 0, 0, 0);
            oacc1 = __builtin_amdgcn_mfma_f32_32x32x16_bf16(pf, vf[4+ks], oacc1, 0, 0, 0);
            lacc  = __builtin_amdgcn_mfma_f32_32x32x16_bf16(pf, onesf,    lacc,  0, 0, 0);
        }
        __builtin_amdgcn_s_setprio(0);
    };

#pragma unroll 1
    for (int ii = 0; ii < 16; ++ii) {
        step(sA0, sA1, sB0, sB1, 0, ii*2);
        step(sB0, sB1, sA0, sA1, 1, ii*2 + 1);
    }

    // epilogue: ctx = (1-a)*O/l + a*c   (lacc rows = q, all cols equal -> direct 1/l)
    const int b = bh >> 4, h = bh & 15;
    const float a1f = 1.f - alpha;
    const float cv0 = alpha * cvec[bh*64 + ln];
    const float cv1 = alpha * cvec[bh*64 + 32 + ln];
#pragma unroll
    for (int m4 = 0; m4 < 4; ++m4) {
#pragma unroll
        for (int r3 = 0; r3 < 4; ++r3) {
            const int row = m4*8 + hi*4 + r3;
            const int s = q0 + row;
            const float iv = frcp(lacc[m4*4 + r3]);
            unsigned short* orow = &ctx[((size_t)(b*2048 + s))*1024 + h*64 + ln];
            orow[0]  = f2bf(a1f * oacc0[m4*4+r3] * iv + cv0);
            orow[32] = f2bf(a1f * oacc1[m4*4+r3] * iv + cv1);
        }
    }
}

// ---------------- launch ----------------
extern "C" void kernel_launch(void* const* d_in, const int* in_sizes, int n_in,
                              void* d_out, int out_size, void* d_ws, size_t ws_size,
                              hipStream_t stream) {
    const float* x     = (const float*)d_in[0];
    const float* ds    = (const float*)d_in[1];
    const float* q_w   = (const float*)d_in[2];
    const float* q_b   = (const float*)d_in[3];
    const float* k_w   = (const float*)d_in[4];
    const float* k_b   = (const float*)d_in[5];
    const float* v_w   = (const float*)d_in[6];
    const float* v_b   = (const float*)d_in[7];
    const float* o_w   = (const float*)d_in[8];
    const float* o_b   = (const float*)d_in[9];
    const float* alpha = (const float*)d_in[10];

    char* ws = (char*)d_ws;
    const size_t MB = 1024 * 1024;
    unsigned short* xb   = (unsigned short*)(ws);            // 8MB, reused as ctx
    unsigned short* wT   = (unsigned short*)(ws + 8  * MB);  // 8MB: wq|wk|wv|wo transposed bf16
    unsigned short* Qb   = (unsigned short*)(ws + 16 * MB);  // 8MB
    unsigned short* Kb   = (unsigned short*)(ws + 24 * MB);  // 8MB
    unsigned short* Vt   = (unsigned short*)(ws + 32 * MB);  // 8MB
    float*          cvec = (float*)         (ws + 40 * MB);  // 8KB
    unsigned short* ctxb = xb;

    const int M = 4096, K = 1024;

    cvt_x_kernel<<<2048, 256, 0, stream>>>(x, xb, M * K / 8);

    dim3 tb(32, 8);
    dim3 tg(32, 32, 4);
    tr_w_kernel<<<tg, tb, 0, stream>>>(q_w, k_w, v_w, o_w, wT);

    dim3 gqkv(24, 32);
    gemm_qkv<<<gqkv, 256, 0, stream>>>(xb, wT, q_b, k_b, v_b, Qb, Kb, Vt);

    hipMemsetAsync(cvec, 0, 32 * 64 * sizeof(float), stream);
    dock_c_kernel<<<256, 256, 0, stream>>>(ds, Vt, cvec);

    attn_kernel<<<512, 256, 0, stream>>>(Qb, Kb, Vt, cvec, alpha, ctxb);

    dim3 go(8, 32);
    gemm_o<<<go, 256, 0, stream>>>(ctxb, wT + (size_t)3 * MB, o_b, (float*)d_out);
}